// Round 8
// baseline (6475.214 us; speedup 1.0000x reference)
//
#include <hip/hip_runtime.h>
#include <math.h>

// ---------------------------------------------------------------------------
// CLSADecoder: 2-layer RowSharedConvLSTM + inter-attn + causal self-attn + head
// B=128, T=64, D=2048 (ROWS=8, CH=32, COLS=8), S=128.
// R7: cell kernels de-bottlenecked per rocprof (1.2e8 residual conflicts were
// the 96 scalar LDS weight reads/thread/t + broadcast bank-alias on h/x):
//  - k_cell1_all: conv weights in 96 VGPRs (loaded once), wlds removed
//    (LDS 60->12 KB), h/x padded 264 with +132 split => conflict-free b128.
//  - k_cell0: same h_lds padding.
// Everything else unchanged from R6 (21 launches).
// ---------------------------------------------------------------------------

typedef _Float16 f16;
typedef _Float16 f16x8 __attribute__((ext_vector_type(8)));
typedef _Float16 f16x4 __attribute__((ext_vector_type(4)));
typedef float  f32x16 __attribute__((ext_vector_type(16)));
typedef float  f32x4v __attribute__((ext_vector_type(4)));
typedef unsigned short u16x8 __attribute__((ext_vector_type(8)));
typedef unsigned short u16x4 __attribute__((ext_vector_type(4)));

#define BD 262144   // 128*2048  (one [B][D] plane)

__device__ __forceinline__ unsigned short f2bf(float x){
  unsigned int u = __builtin_bit_cast(unsigned int, x);
  u += 0x7fffu + ((u >> 16) & 1u);
  return (unsigned short)(u >> 16);
}
__device__ __forceinline__ float bf2f(unsigned short h){
  unsigned int u = ((unsigned int)h) << 16;
  return __builtin_bit_cast(float, u);
}
__device__ __forceinline__ float sigmoidf_(float x){
  return 1.0f / (1.0f + __expf(-x));
}
__device__ __forceinline__ void g2l16(const void* g, void* l){
  __builtin_amdgcn_global_load_lds(
      (const __attribute__((address_space(1))) unsigned int*)g,
      (__attribute__((address_space(3))) unsigned int*)l,
      16, 0, 0);
}

// ---------------------------------------------------------------------------
// transpose f32 weight [K][N] -> f16 plane [N][K]
// ---------------------------------------------------------------------------
__global__ __launch_bounds__(256) void k_transpose_f16(
    const float* __restrict__ src, f16* __restrict__ dhi,
    const int K, const int N)
{
  __shared__ float tile[32][33];
  const int n0 = blockIdx.x * 32, k0 = blockIdx.y * 32;
  const int tx = threadIdx.x & 31, ty = threadIdx.x >> 5;
  #pragma unroll
  for (int ii = 0; ii < 4; ++ii){
    const int k = k0 + ty + ii*8, n = n0 + tx;
    float v = (n < N) ? src[(size_t)k * N + n] : 0.0f;
    tile[ty + ii*8][tx] = v;
  }
  __syncthreads();
  #pragma unroll
  for (int ii = 0; ii < 4; ++ii){
    const int n = n0 + ty + ii*8, k = k0 + tx;
    dhi[(size_t)n * K + k] = (f16)tile[tx][ty + ii*8];
  }
}

__global__ void k_f32_to_bf16(const float* __restrict__ src,
                              unsigned short* __restrict__ dst, const int n4)
{
  const int i = blockIdx.x * 256 + threadIdx.x;
  if (i < n4){
    f32x4v v = *reinterpret_cast<const f32x4v*>(src + (size_t)i * 4);
    u16x4 o;
    #pragma unroll
    for (int j = 0; j < 4; ++j) o[j] = f2bf(v[j]);
    *reinterpret_cast<u16x4*>(dst + (size_t)i * 4) = o;
  }
}

// pack cell1 conv weights: wp[(icg*6 + j)*128 + gc], j 0..2 ch taps, 3..5 cx.
__global__ void k_pack_cellw(const float* __restrict__ chw,
                             const float* __restrict__ cxw,
                             unsigned short* __restrict__ wp)
{
  const int i = blockIdx.x * 256 + threadIdx.x;   // i = gc*32 + icg
  if (i < 128 * 32){
    const int gc = i >> 5, icg = i & 31;
    #pragma unroll
    for (int k = 0; k < 3; ++k){
      wp[(icg*6 + k)*128 + gc]     = f2bf(chw[i*3 + k]);
      wp[(icg*6 + 3 + k)*128 + gc] = f2bf(cxw[i*3 + k]);
    }
  }
}

// ---------------------------------------------------------------------------
// Layer-0 ConvLSTM for ALL 64 steps. Block=(b,row).
// h_lds padded 264: channel ic stored at ic*8+col + (ic>=16 ? 4 : 0) so the
// two ih broadcast groups hit disjoint bank quads (conflict-free b128).
// ---------------------------------------------------------------------------
__global__ __launch_bounds__(256) void k_cell0(
    const float* __restrict__ x_flat,
    const float* __restrict__ h0, const float* __restrict__ c0,
    const float* __restrict__ cxw, const float* __restrict__ cxb,
    const float* __restrict__ chw, const float* __restrict__ chb,
    f16* __restrict__ hrawHi, f16* __restrict__ hrawLo)     // [T][B][2048]
{
  const int b = blockIdx.x >> 3, row = blockIdx.x & 7;
  const int tid = threadIdx.x;
  __shared__ float h_lds[264];
  __shared__ float x_lds[8];
  __shared__ float P[128][2][9];
  const int gc = tid >> 1, ih = tid & 1;
  float wh[16][3];
  #pragma unroll
  for (int icl = 0; icl < 16; ++icl)
    #pragma unroll
    for (int k = 0; k < 3; ++k)
      wh[icl][k] = chw[(gc*32 + ih*16 + icl)*3 + k];
  const float wx0 = cxw[gc*3+0], wx1 = cxw[gc*3+1], wx2 = cxw[gc*3+2];
  const float bsum = cxb[gc] + chb[gc];
  const int ic = tid >> 3, col = tid & 7;
  const size_t dg = (size_t)b*2048 + row*256 + tid;
  const int wofs = tid + ((tid >> 7) << 2);    // padded write index
  const int hbase = ih * 132;                  // padded read base per ih group
  float c_reg = c0[dg];
  h_lds[wofs] = h0[dg];
  float xnext = (tid < 8) ? x_flat[((size_t)b*64 + 0)*64 + row*8 + tid] : 0.f;
  __syncthreads();
  for (int t = 0; t < 64; ++t){
    if (tid < 8) x_lds[tid] = xnext;
    __syncthreads();
    if (t < 63 && tid < 8)
      xnext = x_flat[((size_t)b*64 + t + 1)*64 + row*8 + tid];
    float g8[8];
    #pragma unroll
    for (int c2 = 0; c2 < 8; ++c2) g8[c2] = 0.f;
    #pragma unroll
    for (int icl = 0; icl < 16; ++icl){
      const float* hb = &h_lds[icl*8 + hbase];
      f32x4v hv0 = *reinterpret_cast<const f32x4v*>(hb);
      f32x4v hv1 = *reinterpret_cast<const f32x4v*>(hb + 4);
      const float hv[8] = {hv0[0],hv0[1],hv0[2],hv0[3],hv1[0],hv1[1],hv1[2],hv1[3]};
      #pragma unroll
      for (int c2 = 0; c2 < 8; ++c2){
        float s = hv[c2] * wh[icl][1];
        if (c2 > 0) s += hv[c2-1] * wh[icl][0];
        if (c2 < 7) s += hv[c2+1] * wh[icl][2];
        g8[c2] += s;
      }
    }
    if (ih == 0){
      #pragma unroll
      for (int c2 = 0; c2 < 8; ++c2){
        float s = x_lds[c2] * wx1 + bsum;
        if (c2 > 0) s += x_lds[c2-1] * wx0;
        if (c2 < 7) s += x_lds[c2+1] * wx2;
        g8[c2] += s;
      }
    }
    #pragma unroll
    for (int c2 = 0; c2 < 8; ++c2) P[gc][ih][c2] = g8[c2];
    __syncthreads();
    const float ipre = P[ic   ][0][col] + P[ic   ][1][col];
    const float fpre = P[ic+32][0][col] + P[ic+32][1][col];
    const float opre = P[ic+64][0][col] + P[ic+64][1][col];
    const float gpre = P[ic+96][0][col] + P[ic+96][1][col];
    const float cn = sigmoidf_(fpre)*c_reg + sigmoidf_(ipre)*tanhf(gpre);
    c_reg = cn;
    const float hn = sigmoidf_(opre)*tanhf(cn);
    const f16 hh = (f16)hn;
    hrawHi[((size_t)t*128 + b)*2048 + row*256 + tid] = hh;
    hrawLo[((size_t)t*128 + b)*2048 + row*256 + tid] = (f16)(hn - (float)hh);
    __syncthreads();
    h_lds[wofs] = hn;
  }
}

// ---------------------------------------------------------------------------
// Layer-1 ConvLSTM for ALL 64 steps. Weights in 96 VGPRs; padded h/x LDS.
// ---------------------------------------------------------------------------
__global__ __launch_bounds__(256) void k_cell1_all(
    const f16* __restrict__ r0Hi, const f16* __restrict__ r0Lo,
    const float* __restrict__ h0s, const float* __restrict__ c0s,
    const unsigned short* __restrict__ wp,     // [(icg*6+j)*128+gc]
    const float* __restrict__ cxb, const float* __restrict__ chb,
    f16* __restrict__ hrw1Hi, f16* __restrict__ hrw1Lo)            // [T][B][2048]
{
  const int b = blockIdx.x >> 3, row = blockIdx.x & 7;
  const int tid = threadIdx.x;
  __shared__ float x_lds[264];
  __shared__ float h_lds[264];
  __shared__ float P[128][2][9];
  const int gc = tid >> 1, ih = tid & 1;
  // conv weights -> registers (once)
  float whr[16][3], wxr[16][3];
  #pragma unroll
  for (int icl = 0; icl < 16; ++icl){
    const int icg = ih*16 + icl;
    #pragma unroll
    for (int k = 0; k < 3; ++k){
      whr[icl][k] = bf2f(wp[(icg*6 + k)*128 + gc]);
      wxr[icl][k] = bf2f(wp[(icg*6 + 3 + k)*128 + gc]);
    }
  }
  const size_t dg = (size_t)b*2048 + row*256 + tid;
  const int ic = tid >> 3, col = tid & 7;
  const float bi = cxb[ic]    + chb[ic];
  const float bf = cxb[ic+32] + chb[ic+32];
  const float bo = cxb[ic+64] + chb[ic+64];
  const float bg = cxb[ic+96] + chb[ic+96];
  const int wofs = tid + ((tid >> 7) << 2);
  const int hbase = ih * 132;
  float c_reg = c0s[dg];
  h_lds[wofs] = h0s[dg];
  float xnext = (float)r0Hi[dg] + (float)r0Lo[dg];
  __syncthreads();
  for (int t = 0; t < 64; ++t){
    x_lds[wofs] = xnext;
    __syncthreads();
    if (t < 63)
      xnext = (float)r0Hi[(size_t)(t+1)*BD + dg] + (float)r0Lo[(size_t)(t+1)*BD + dg];
    {
      float g8[8];
      #pragma unroll
      for (int c2 = 0; c2 < 8; ++c2) g8[c2] = 0.f;
      #pragma unroll
      for (int icl = 0; icl < 16; ++icl){
        const float* hb = &h_lds[icl*8 + hbase];
        const float* xb = &x_lds[icl*8 + hbase];
        f32x4v hv0 = *reinterpret_cast<const f32x4v*>(hb);
        f32x4v hv1 = *reinterpret_cast<const f32x4v*>(hb + 4);
        f32x4v xv0 = *reinterpret_cast<const f32x4v*>(xb);
        f32x4v xv1 = *reinterpret_cast<const f32x4v*>(xb + 4);
        const float hv[8] = {hv0[0],hv0[1],hv0[2],hv0[3],hv1[0],hv1[1],hv1[2],hv1[3]};
        const float xv[8] = {xv0[0],xv0[1],xv0[2],xv0[3],xv1[0],xv1[1],xv1[2],xv1[3]};
        const float wh0 = whr[icl][0], wh1 = whr[icl][1], wh2 = whr[icl][2];
        const float wx0 = wxr[icl][0], wx1 = wxr[icl][1], wx2 = wxr[icl][2];
        #pragma unroll
        for (int c2 = 0; c2 < 8; ++c2){
          float s = hv[c2]*wh1 + xv[c2]*wx1;
          if (c2 > 0) s += hv[c2-1]*wh0 + xv[c2-1]*wx0;
          if (c2 < 7) s += hv[c2+1]*wh2 + xv[c2+1]*wx2;
          g8[c2] += s;
        }
      }
      #pragma unroll
      for (int c2 = 0; c2 < 8; ++c2) P[gc][ih][c2] = g8[c2];
    }
    __syncthreads();
    {
      const float ipre = P[ic   ][0][col] + P[ic   ][1][col] + bi;
      const float fpre = P[ic+32][0][col] + P[ic+32][1][col] + bf;
      const float opre = P[ic+64][0][col] + P[ic+64][1][col] + bo;
      const float gpre = P[ic+96][0][col] + P[ic+96][1][col] + bg;
      const float cn = sigmoidf_(fpre)*c_reg + sigmoidf_(ipre)*tanhf(gpre);
      c_reg = cn;
      const float hraw = sigmoidf_(opre)*tanhf(cn);
      const f16 hh = (f16)hraw;
      hrw1Hi[(size_t)t*BD + dg] = hh;
      hrw1Lo[(size_t)t*BD + dg] = (f16)(hraw - (float)hh);
      __syncthreads();           // all P reads done before next iter overwrites
      h_lds[wofs] = hraw;
    }
  }
}

// ---------------------------------------------------------------------------
// Batched inter-attention (both layers, all t): block (b, t), 8 waves x 16
// encoder rows, online softmax, deterministic 8-way LDS combine.
// ---------------------------------------------------------------------------
__global__ __launch_bounds__(512) void k_inter_b(
    const unsigned short* __restrict__ encBf,
    const f16* __restrict__ stHi, const f16* __restrict__ stLo,   // [T][B][2048]
    f16* __restrict__ ctxHi, f16* __restrict__ ctxLo)
{
  const int b = blockIdx.x;
  const size_t so = (size_t)blockIdx.y * BD + (size_t)b * 2048;
  const int tid = threadIdx.x;
  const int lane = tid & 63, wv = tid >> 6;
  __shared__ float wav[8][2048];
  __shared__ float wm[8], wl[8];
  float sv[32], av[32];
  #pragma unroll
  for (int p = 0; p < 4; ++p){
    const int d = (p*64 + lane)*8;
    f16x8 hh = *reinterpret_cast<const f16x8*>(stHi + so + d);
    f16x8 ll = *reinterpret_cast<const f16x8*>(stLo + so + d);
    #pragma unroll
    for (int j = 0; j < 8; ++j){ sv[p*8+j] = (float)hh[j] + (float)ll[j]; av[p*8+j] = 0.f; }
  }
  float m = -INFINITY, l = 0.f;
  const int s0 = wv*16;
  for (int r = 0; r < 16; ++r){
    const unsigned short* er = encBf + ((size_t)b*128 + s0 + r)*2048;
    float ef[32];
    float dot = 0.f;
    #pragma unroll
    for (int p = 0; p < 4; ++p){
      u16x8 ev = *reinterpret_cast<const u16x8*>(er + (p*64 + lane)*8);
      #pragma unroll
      for (int j = 0; j < 8; ++j){ const float e = bf2f(ev[j]); ef[p*8+j] = e; dot += e * sv[p*8+j]; }
    }
    #pragma unroll
    for (int off = 1; off < 64; off <<= 1) dot += __shfl_xor(dot, off);
    if (dot > m){
      const float scf = __expf(m - dot);
      l *= scf;
      #pragma unroll
      for (int q = 0; q < 32; ++q) av[q] *= scf;
      m = dot;
    }
    const float pp = __expf(dot - m);
    l += pp;
    #pragma unroll
    for (int q = 0; q < 32; ++q) av[q] += pp * ef[q];
  }
  #pragma unroll
  for (int p = 0; p < 4; ++p){
    const int d = (p*64 + lane)*8;
    f32x4v v0, v1;
    #pragma unroll
    for (int j = 0; j < 4; ++j){ v0[j] = av[p*8+j]; v1[j] = av[p*8+4+j]; }
    *reinterpret_cast<f32x4v*>(&wav[wv][d]) = v0;
    *reinterpret_cast<f32x4v*>(&wav[wv][d+4]) = v1;
  }
  if (lane == 0){ wm[wv] = m; wl[wv] = l; }
  __syncthreads();
  float M = wm[0];
  #pragma unroll
  for (int i = 1; i < 8; ++i) M = fmaxf(M, wm[i]);
  float U[8];
  float L = 0.f;
  #pragma unroll
  for (int i = 0; i < 8; ++i){ U[i] = __expf(wm[i] - M); L += wl[i] * U[i]; }
  const float Linv = 1.f / L;
  const int d0 = tid * 4;
  float acc[4] = {0.f, 0.f, 0.f, 0.f};
  #pragma unroll
  for (int w = 0; w < 8; ++w){
    f32x4v v = *reinterpret_cast<const f32x4v*>(&wav[w][d0]);
    #pragma unroll
    for (int j = 0; j < 4; ++j) acc[j] += U[w] * v[j];
  }
  f16x4 hh, ll;
  #pragma unroll
  for (int j = 0; j < 4; ++j){
    const float v = acc[j] * Linv;
    hh[j] = (f16)v;
    ll[j] = (f16)(v - (float)hh[j]);
  }
  *reinterpret_cast<f16x4*>(ctxHi + so + d0) = hh;
  *reinterpret_cast<f16x4*>(ctxLo + so + d0) = ll;
}

// ---------------------------------------------------------------------------
// Batched full-K ia GEMM (all t): p[t] = tanh([A0|A1]@W + bias), f16 hi/lo.
// Grid (32 nt, 64 t). K=4096, f16 2-pass MFMA, global_load_lds double-buffer.
// ---------------------------------------------------------------------------
__global__ __launch_bounds__(256, 2) void k_gemm_full(
    const f16* __restrict__ a0Hi, const f16* __restrict__ a0Lo,
    const f16* __restrict__ a1Hi, const f16* __restrict__ a1Lo,
    const f16* __restrict__ wHp, const float* __restrict__ bias,
    f16* __restrict__ outHi, f16* __restrict__ outLo)
{
  const int nt = blockIdx.x, t = blockIdx.y;
  const size_t tb = (size_t)t * BD;
  const int tid = threadIdx.x;
  const int lane = tid & 63, wv = tid >> 6;
  __shared__ __align__(16) char lds[81920];
  const f16* wH = wHp + (size_t)(nt*64)*4096;

  auto stage = [&](int buf, int ki){
    char* lb = lds + buf*40960;
    const f16* aH = ((ki < 32) ? a0Hi : a1Hi) + tb;
    const f16* aL = ((ki < 32) ? a0Lo : a1Lo) + tb;
    const int ke = (ki & 31) * 64;
    #pragma unroll
    for (int i = 0; i < 4; ++i){
      const int c = i*256 + tid, row = c >> 3;
      const int srcb = ((c & 7)*16) ^ ((row & 7) << 4);
      g2l16((const char*)(aH + (size_t)row*2048 + ke) + srcb, lb + c*16);
      g2l16((const char*)(aL + (size_t)row*2048 + ke) + srcb, lb + 16384 + c*16);
    }
    #pragma unroll
    for (int i = 0; i < 2; ++i){
      const int c = i*256 + tid, row = c >> 3;
      const int srcb = ((c & 7)*16) ^ ((row & 7) << 4);
      g2l16((const char*)(wH + (size_t)row*4096 + ki*64) + srcb, lb + 32768 + c*16);
    }
  };

  f32x16 acc0, acc1;
  #pragma unroll
  for (int r = 0; r < 16; ++r){ acc0[r] = 0.f; acc1[r] = 0.f; }
  const int rA = wv*32 + (lane & 31);
  const int kb = lane >> 5;
  const int rB0 = lane & 31;
  const int aswz = (rA & 7) << 4;
  const int bswz = (rB0 & 7) << 4;

  stage(0, 0);
  __syncthreads();
  for (int ki = 0; ki < 64; ++ki){
    const int buf = ki & 1;
    if (ki < 63) stage(buf ^ 1, ki + 1);
    const char* lb = lds + buf*40960;
    #pragma unroll
    for (int s = 0; s < 4; ++s){
      const int cb = s*32 + kb*16;
      f16x8 ah  = *reinterpret_cast<const f16x8*>(lb + rA*128 + (cb ^ aswz));
      f16x8 al  = *reinterpret_cast<const f16x8*>(lb + 16384 + rA*128 + (cb ^ aswz));
      f16x8 b0h = *reinterpret_cast<const f16x8*>(lb + 32768 + rB0*128 + (cb ^ bswz));
      f16x8 b1h = *reinterpret_cast<const f16x8*>(lb + 32768 + 4096 + rB0*128 + (cb ^ bswz));
      acc0 = __builtin_amdgcn_mfma_f32_32x32x16_f16(ah, b0h, acc0, 0, 0, 0);
      acc1 = __builtin_amdgcn_mfma_f32_32x32x16_f16(ah, b1h, acc1, 0, 0, 0);
      acc0 = __builtin_amdgcn_mfma_f32_32x32x16_f16(al, b0h, acc0, 0, 0, 0);
      acc1 = __builtin_amdgcn_mfma_f32_32x32x16_f16(al, b1h, acc1, 0, 0, 0);
    }
    __syncthreads();
  }

  const int col0 = nt*64 + (lane & 31);
  const float b0 = bias[col0], b1 = bias[col0 + 32];
  const int rowBase = wv*32 + 4*kb;
  #pragma unroll
  for (int r = 0; r < 16; ++r){
    const int rr = rowBase + (r & 3) + 8*(r >> 2);
    const size_t o = tb + (size_t)rr*2048 + col0;
    const float p = tanhf(acc0[r] + b0);
    const float q = tanhf(acc1[r] + b1);
    const f16 ph = (f16)p, qh = (f16)q;
    outHi[o]      = ph;  outLo[o]      = (f16)(p - (float)ph);
    outHi[o + 32] = qh;  outLo[o + 32] = (f16)(q - (float)qh);
  }
}

// ---------------------------------------------------------------------------
// Batched sa GEMM (all t): A = p hi/lo, W = [Wlow^T|Wup^T] ([4096][2048]).
// nt<32 -> Y (f32, raw); nt>=32 -> G (f16). Grid (64 nt, 64 t), K=2048.
// ---------------------------------------------------------------------------
__global__ __launch_bounds__(256, 2) void k_gemm_full2(
    const f16* __restrict__ aHi, const f16* __restrict__ aLo,   // [T][B][2048]
    const f16* __restrict__ wSp,                                // [4096][2048]
    float* __restrict__ Y, f16* __restrict__ G)                 // [T][B][2048]
{
  const int nt = blockIdx.x, t = blockIdx.y;
  const size_t tb = (size_t)t * BD;
  const int tid = threadIdx.x;
  const int lane = tid & 63, wv = tid >> 6;
  __shared__ __align__(16) char lds[81920];
  const f16* wH = wSp + (size_t)(nt*64)*2048;
  const f16* aH = aHi + tb;
  const f16* aL = aLo + tb;

  auto stage = [&](int buf, int ki){
    char* lb = lds + buf*40960;
    const int ke = ki*64;
    #pragma unroll
    for (int i = 0; i < 4; ++i){
      const int c = i*256 + tid, row = c >> 3;
      const int srcb = ((c & 7)*16) ^ ((row & 7) << 4);
      g2l16((const char*)(aH + (size_t)row*2048 + ke) + srcb, lb + c*16);
      g2l16((const char*)(aL + (size_t)row*2048 + ke) + srcb, lb + 16384 + c*16);
    }
    #pragma unroll
    for (int i = 0; i < 2; ++i){
      const int c = i*256 + tid, row = c >> 3;
      const int srcb = ((c & 7)*16) ^ ((row & 7) << 4);
      g2l16((const char*)(wH + (size_t)row*2048 + ke) + srcb, lb + 32768 + c*16);
    }
  };

  f32x16 acc0, acc1;
  #pragma unroll
  for (int r = 0; r < 16; ++r){ acc0[r] = 0.f; acc1[r] = 0.f; }
  const int rA = wv*32 + (lane & 31);
  const int kb = lane >> 5;
  const int rB0 = lane & 31;
  const int aswz = (rA & 7) << 4;
  const int bswz = (rB0 & 7) << 4;

  stage(0, 0);
  __syncthreads();
  for (int ki = 0; ki < 32; ++ki){
    const int buf = ki & 1;
    if (ki < 31) stage(buf ^ 1, ki + 1);
    const char* lb = lds + buf*40960;
    #pragma unroll
    for (int s = 0; s < 4; ++s){
      const int cb = s*32 + kb*16;
      f16x8 ah  = *reinterpret_cast<const f16x8*>(lb + rA*128 + (cb ^ aswz));
      f16x8 al  = *reinterpret_cast<const f16x8*>(lb + 16384 + rA*128 + (cb ^ aswz));
      f16x8 b0h = *reinterpret_cast<const f16x8*>(lb + 32768 + rB0*128 + (cb ^ bswz));
      f16x8 b1h = *reinterpret_cast<const f16x8*>(lb + 32768 + 4096 + rB0*128 + (cb ^ bswz));
      acc0 = __builtin_amdgcn_mfma_f32_32x32x16_f16(ah, b0h, acc0, 0, 0, 0);
      acc1 = __builtin_amdgcn_mfma_f32_32x32x16_f16(ah, b1h, acc1, 0, 0, 0);
      acc0 = __builtin_amdgcn_mfma_f32_32x32x16_f16(al, b0h, acc0, 0, 0, 0);
      acc1 = __builtin_amdgcn_mfma_f32_32x32x16_f16(al, b1h, acc1, 0, 0, 0);
    }
    __syncthreads();
  }

  const int col0 = nt*64 + (lane & 31);
  const int rowBase = wv*32 + 4*kb;
  if (nt < 32){
    float* yp = Y + tb + col0;
    #pragma unroll
    for (int r = 0; r < 16; ++r){
      const int rr = rowBase + (r & 3) + 8*(r >> 2);
      yp[(size_t)rr*2048]      = acc0[r];
      yp[(size_t)rr*2048 + 32] = acc1[r];
    }
  } else {
    f16* gp = G + tb + (col0 - 2048);
    #pragma unroll
    for (int r = 0; r < 16; ++r){
      const int rr = rowBase + (r & 3) + 8*(r >> 2);
      gp[(size_t)rr*2048]      = (f16)acc0[r];
      gp[(size_t)rr*2048 + 32] = (f16)acc1[r];
    }
  }
}

// ---------------------------------------------------------------------------
// Self-attention refine chain (persistent over t). Block per b, 512 threads.
// ---------------------------------------------------------------------------
__global__ __launch_bounds__(512) void k_selfchain(
    const f16* __restrict__ pHi, const f16* __restrict__ pLo,   // [T][B][2048]
    const float* __restrict__ Y, const f16* __restrict__ G,     // [T][B][2048]
    const float* __restrict__ bias,
    f16* __restrict__ rHi, f16* __restrict__ rLo)               // [T][B][2048]
{
  const int b = blockIdx.x;
  const int tid = threadIdx.x, lane = tid & 63, wv = tid >> 6;   // 8 waves
  __shared__ float sc[64];
  __shared__ float a_lds[64];
  const int d0 = tid * 4;
  f32x4v bb = *reinterpret_cast<const f32x4v*>(bias + d0);
  for (int t = 0; t < 64; ++t){
    const size_t pb = ((size_t)t*128 + b)*2048;
    if (t > 0){
      float hreg[32];
      #pragma unroll
      for (int jj = 0; jj < 4; ++jj){
        const int d = (jj*64 + lane)*8;
        f16x8 h8 = *reinterpret_cast<const f16x8*>(pHi + pb + d);
        f16x8 l8 = *reinterpret_cast<const f16x8*>(pLo + pb + d);
        #pragma unroll
        for (int j = 0; j < 8; ++j) hreg[jj*8+j] = (float)h8[j] + (float)l8[j];
      }
      for (int i = wv; i < t; i += 8){
        const f16* rh = rHi + ((size_t)i*128 + b)*2048;
        const f16* rl = rLo + ((size_t)i*128 + b)*2048;
        float dot = 0.f;
        #pragma unroll
        for (int jj = 0; jj < 4; ++jj){
          const int d = (jj*64 + lane)*8;
          f16x8 h8 = *reinterpret_cast<const f16x8*>(rh + d);
          f16x8 l8 = *reinterpret_cast<const f16x8*>(rl + d);
          #pragma unroll
          for (int j = 0; j < 8; ++j)
            dot += ((float)h8[j] + (float)l8[j]) * hreg[jj*8+j];
        }
        #pragma unroll
        for (int off = 1; off < 64; off <<= 1) dot += __shfl_xor(dot, off);
        if (lane == 0) sc[i] = dot;
      }
      __syncthreads();
      if (tid < 64){
        const float s = (tid < t) ? sc[tid] : -INFINITY;
        float mm = s;
        #pragma unroll
        for (int off = 1; off < 64; off <<= 1) mm = fmaxf(mm, __shfl_xor(mm, off));
        const float e = (tid < t) ? __expf(s - mm) : 0.f;
        float sum = e;
        #pragma unroll
        for (int off = 1; off < 64; off <<= 1) sum += __shfl_xor(sum, off);
        a_lds[tid] = e / sum;
      }
      __syncthreads();
    }
    float y[4];
    {
      f32x4v yv = *reinterpret_cast<const f32x4v*>(Y + (size_t)t*BD + (size_t)b*2048 + d0);
      #pragma unroll
      for (int j = 0; j < 4; ++j) y[j] = yv[j] + bb[j];
    }
    if (t > 0){
      for (int i = 0; i < t; ++i){
        const float a = a_lds[i];
        f16x4 g4 = *reinterpret_cast<const f16x4*>(G + ((size_t)i*128 + b)*2048 + d0);
        #pragma unroll
        for (int j = 0; j < 4; ++j) y[j] += a * (float)g4[j];
      }
    }
    f16x4 hh, ll;
    #pragma unroll
    for (int j = 0; j < 4; ++j){
      const float v = tanhf(y[j]);
      hh[j] = (f16)v;
      ll[j] = (f16)(v - (float)hh[j]);
    }
    *reinterpret_cast<f16x4*>(rHi + pb + d0) = hh;
    *reinterpret_cast<f16x4*>(rLo + pb + d0) = ll;
    __syncthreads();   // r[t] stores drained before t+1 scores read them
  }
}

// ---------------------------------------------------------------------------
// Head stage 1: z1 = relu(r1(8192x2048) @ hw1 + hb1), f16 2-pass MFMA
// ---------------------------------------------------------------------------
__global__ __launch_bounds__(256) void k_headgemm(
    const f16* __restrict__ aHi, const f16* __restrict__ aLo,
    const f16* __restrict__ w1H,   // [224][2048]
    const float* __restrict__ hb1,
    float* __restrict__ z1)        // [8192][224]
{
  const int mb = blockIdx.x;
  const int nt = blockIdx.y;
  const int lane = threadIdx.x & 63, wv = threadIdx.x >> 6;
  const int rowA = mb*128 + wv*32 + (lane & 31);
  const int kb = lane >> 5;
  const int n = nt*32 + (lane & 31);
  const f16* pAH = aHi + (size_t)rowA*2048 + kb*8;
  const f16* pAL = aLo + (size_t)rowA*2048 + kb*8;
  const f16* pBH = w1H + (size_t)n*2048 + kb*8;
  f32x16 acc;
  #pragma unroll
  for (int r = 0; r < 16; ++r) acc[r] = 0.f;
  #pragma unroll 4
  for (int s = 0; s < 128; ++s){
    f16x8 ah = *reinterpret_cast<const f16x8*>(pAH + s*16);
    f16x8 al = *reinterpret_cast<const f16x8*>(pAL + s*16);
    f16x8 bh = *reinterpret_cast<const f16x8*>(pBH + s*16);
    acc = __builtin_amdgcn_mfma_f32_32x32x16_f16(ah, bh, acc, 0, 0, 0);
    acc = __builtin_amdgcn_mfma_f32_32x32x16_f16(al, bh, acc, 0, 0, 0);
  }
  const float bias = (n < 200) ? hb1[n] : 0.f;
  const int rowBase = mb*128 + wv*32 + 4*kb;
  #pragma unroll
  for (int r = 0; r < 16; ++r){
    const int rr = rowBase + (r & 3) + 8*(r >> 2);
    z1[(size_t)rr*224 + n] = fmaxf(acc[r] + bias, 0.f);
  }
}

// Head stage 2
__global__ __launch_bounds__(256) void k_head2(
    const float* __restrict__ z1,
    const float* __restrict__ hw2, const float* __restrict__ hb2,
    const float* __restrict__ hw3, const float* __restrict__ hb3,
    float* __restrict__ out)
{
  const int r0 = blockIdx.x * 64;
  const int tid = threadIdx.x;
  __shared__ float zl[64][200];
  __shared__ float z2[64][50];
  for (int i = tid; i < 64*200; i += 256){
    const int r = i / 200, n = i % 200;
    zl[r][n] = z1[(size_t)(r0 + r)*224 + n];
  }
  __syncthreads();
  for (int i = tid; i < 64*50; i += 256){
    const int r = i / 50, n = i % 50;
    float s = hb2[n];
    for (int k = 0; k < 200; ++k) s += zl[r][k] * hw2[k*50 + n];
    z2[r][n] = fmaxf(s, 0.f);
  }
  __syncthreads();
  for (int i = tid; i < 128; i += 256){
    const int r = i >> 1, c = i & 1;
    float s = hb3[c];
    for (int k = 0; k < 50; ++k) s += z2[r][k] * hw3[k*2 + c];
    const int rg = r0 + r;
    const int tt = rg >> 7, b = rg & 127;
    out[(size_t)b*128 + tt*2 + c] = s;
  }
}

// ---------------------------------------------------------------------------
extern "C" void kernel_launch(void* const* d_in, const int* in_sizes, int n_in,
                              void* d_out, int out_size, void* d_ws, size_t ws_size,
                              hipStream_t stream)
{
  (void)in_sizes; (void)n_in; (void)out_size; (void)ws_size;
  const float* x_flat = (const float*)d_in[0];
  const float* enc    = (const float*)d_in[1];
  const float* h0     = (const float*)d_in[2];
  const float* c0     = (const float*)d_in[3];
  const float* cx_w0  = (const float*)d_in[4];
  const float* cx_b0  = (const float*)d_in[5];
  const float* ch_w0  = (const float*)d_in[6];
  const float* ch_b0  = (const float*)d_in[7];
  const float* cx_w1  = (const float*)d_in[8];
  const float* cx_b1  = (const float*)d_in[9];
  const float* ch_w1  = (const float*)d_in[10];
  const float* ch_b1  = (const float*)d_in[11];
  const float* ia_w0  = (const float*)d_in[12];
  const float* ia_b0  = (const float*)d_in[13];
  const float* sa_w0  = (const float*)d_in[14];
  const float* sa_b0  = (const float*)d_in[15];
  const float* ia_w1  = (const float*)d_in[16];
  const float* ia_b1  = (const float*)d_in[17];
  const float* sa_w1  = (const float*)d_in[18];
  const float* sa_b1  = (const float*)d_in[19];
  const float* hw1    = (const float*)d_in[20];
  const float* hb1    = (const float*)d_in[21];
  const float* hw2    = (const float*)d_in[22];
  const float* hb2    = (const float*)d_in[23];
  const float* hw3    = (const float*)d_in[24];
  const float* hb3    = (const float*)d_in[25];
  float* out = (float*)d_out;

  char* ws = (char*)d_ws;
  size_t off = 0;
  auto alloc = [&](size_t bytes) -> char* {
    char* p = ws + off;
    off += (bytes + 255) & ~(size_t)255;
    return p;
  };
  const size_t WPLANE = (size_t)2048*4096*2;   // 16 MiB
  const size_t TPLANE = (size_t)64*BD*2;       // 32 MiB, [T][B][D] f16
  f16* wIa0 = (f16*)alloc(WPLANE);
  f16* wSa0 = (f16*)alloc(WPLANE);   // [4096][2048]: Wlow^T rows 0..2047, Wup^T rows 2048..
  f16* wIa1 = (f16*)alloc(WPLANE);
  f16* wSa1 = (f16*)alloc(WPLANE);
  f16* w1H  = (f16*)alloc((size_t)224*2048*2);
  unsigned short* encBf = (unsigned short*)alloc((size_t)128*128*2048*2);
  f16* S1 = (f16*)alloc(TPLANE);
  f16* S2 = (f16*)alloc(TPLANE);
  f16* S3 = (f16*)alloc(TPLANE);
  f16* S4 = (f16*)alloc(TPLANE);
  f16* S5 = (f16*)alloc(TPLANE);
  f16* S6 = (f16*)alloc(TPLANE);
  f16* S7 = (f16*)alloc(TPLANE);
  f16* S8 = (f16*)alloc(TPLANE);
  unsigned short* wpack1 = (unsigned short*)alloc((size_t)128*32*6*2);
  // total ws ~= 385 MiB. Alias names (lifetimes verified disjoint):
  f16*  hr0AHi = S1;  f16* hr0ALo = S2;
  f16*  ctx0Hi = S3;  f16* ctx0Lo = S4;
  f16*  p0Hi   = S5;  f16* p0Lo   = S6;
  float* Y0 = (float*)S1;                    // 64 MiB over S1+S2 (contiguous)
  f16*  G0  = S3;
  f16*  r0Hi = S7;    f16* r0Lo   = S8;
  f16*  hrw1Hi = S5;  f16* hrw1Lo = S6;
  f16*  ctx1Hi = S1;  f16* ctx1Lo = S2;
  f16*  p1Hi = S7;    f16* p1Lo   = S8;
  float* Y1 = (float*)S1;                    // 64 MiB over S1+S2
  f16*  G1  = S4;
  f16*  r1Hi = S5;    f16* r1Lo   = S3;
  float* z1 = (float*)wSa0;                  // head scratch (wSa0 dead by then)

  // ---- prologue -----------------------------------------------------------
  k_transpose_f16<<<dim3(64,128),256,0,stream>>>(ia_w0, wIa0, 4096, 2048);
  k_transpose_f16<<<dim3(64,128),256,0,stream>>>(ia_w1, wIa1, 4096, 2048);
  k_transpose_f16<<<dim3(64,64),256,0,stream>>>(sa_w0, wSa0, 2048, 2048);
  k_transpose_f16<<<dim3(64,64),256,0,stream>>>(sa_w0 + (size_t)2048*2048,
                                                wSa0 + (size_t)2048*2048, 2048, 2048);
  k_transpose_f16<<<dim3(64,64),256,0,stream>>>(sa_w1, wSa1, 2048, 2048);
  k_transpose_f16<<<dim3(64,64),256,0,stream>>>(sa_w1 + (size_t)2048*2048,
                                                wSa1 + (size_t)2048*2048, 2048, 2048);
  k_transpose_f16<<<dim3(7,64),256,0,stream>>>(hw1, w1H, 2048, 200);
  k_f32_to_bf16<<<(128*128*2048/4 + 255)/256, 256, 0, stream>>>(enc, encBf, 128*128*2048/4);
  k_pack_cellw<<<16,256,0,stream>>>(ch_w1, cx_w1, wpack1);

  // ---- layer 0 (fully batched + one persistent chain) ---------------------
  k_cell0<<<1024,256,0,stream>>>(x_flat, h0, c0, cx_w0, cx_b0, ch_w0, ch_b0,
                                 hr0AHi, hr0ALo);
  k_inter_b<<<dim3(128,64),512,0,stream>>>(encBf, hr0AHi, hr0ALo, ctx0Hi, ctx0Lo);
  k_gemm_full<<<dim3(32,64),256,0,stream>>>(hr0AHi, hr0ALo, ctx0Hi, ctx0Lo,
                                            wIa0, ia_b0, p0Hi, p0Lo);
  k_gemm_full2<<<dim3(64,64),256,0,stream>>>(p0Hi, p0Lo, wSa0, Y0, G0);
  k_selfchain<<<128,512,0,stream>>>(p0Hi, p0Lo, Y0, G0, sa_b0, r0Hi, r0Lo);

  // ---- layer 1 (persistent cell + fully batched + one persistent chain) ---
  k_cell1_all<<<1024,256,0,stream>>>(r0Hi, r0Lo,
                                     h0 + (size_t)128*2048, c0 + (size_t)128*2048,
                                     wpack1, cx_b1, ch_b1, hrw1Hi, hrw1Lo);
  k_inter_b<<<dim3(128,64),512,0,stream>>>(encBf, hrw1Hi, hrw1Lo, ctx1Hi, ctx1Lo);
  k_gemm_full<<<dim3(32,64),256,0,stream>>>(hrw1Hi, hrw1Lo, ctx1Hi, ctx1Lo,
                                            wIa1, ia_b1, p1Hi, p1Lo);
  k_gemm_full2<<<dim3(64,64),256,0,stream>>>(p1Hi, p1Lo, wSa1, Y1, G1);
  k_selfchain<<<128,512,0,stream>>>(p1Hi, p1Lo, Y1, G1, sa_b1, r1Hi, r1Lo);

  // ---- head (batched over all t,b) ----------------------------------------
  k_headgemm<<<dim3(64,7),256,0,stream>>>(r1Hi, r1Lo, w1H, hb1, z1);
  k_head2<<<128,256,0,stream>>>(z1, hw2, hb2, hw3, hb3, out);
}

// Round 9
// 5469.542 us; speedup vs baseline: 1.1839x; 1.1839x over previous
//
#include <hip/hip_runtime.h>
#include <math.h>

// ---------------------------------------------------------------------------
// CLSADecoder: 2-layer RowSharedConvLSTM + inter-attn + causal self-attn + head
// B=128, T=64, D=2048 (ROWS=8, CH=32, COLS=8), S=128.
// R8: R7 regressed (VGPR 256 cap -> scratch spills: WRITE_SIZE 65->174MB).
// cell1_all weights moved back to LDS but packed 2-taps-per-u32 in layout
// [(icg*3+w)*128 + gc]: bank = gc mod 32 (conflict-free, lane pairs
// broadcast), 48 LDS issues/thread/t instead of 96, zero weight VGPRs.
// Keeps R7's padded h/x (conflict-free b128) and padded P.
// ---------------------------------------------------------------------------

typedef _Float16 f16;
typedef _Float16 f16x8 __attribute__((ext_vector_type(8)));
typedef _Float16 f16x4 __attribute__((ext_vector_type(4)));
typedef float  f32x16 __attribute__((ext_vector_type(16)));
typedef float  f32x4v __attribute__((ext_vector_type(4)));
typedef unsigned short u16x8 __attribute__((ext_vector_type(8)));
typedef unsigned short u16x4 __attribute__((ext_vector_type(4)));

#define BD 262144   // 128*2048  (one [B][D] plane)

__device__ __forceinline__ unsigned short f2bf(float x){
  unsigned int u = __builtin_bit_cast(unsigned int, x);
  u += 0x7fffu + ((u >> 16) & 1u);
  return (unsigned short)(u >> 16);
}
__device__ __forceinline__ float bf2f(unsigned short h){
  unsigned int u = ((unsigned int)h) << 16;
  return __builtin_bit_cast(float, u);
}
__device__ __forceinline__ float sigmoidf_(float x){
  return 1.0f / (1.0f + __expf(-x));
}
__device__ __forceinline__ void g2l16(const void* g, void* l){
  __builtin_amdgcn_global_load_lds(
      (const __attribute__((address_space(1))) unsigned int*)g,
      (__attribute__((address_space(3))) unsigned int*)l,
      16, 0, 0);
}

// ---------------------------------------------------------------------------
// transpose f32 weight [K][N] -> f16 plane [N][K]
// ---------------------------------------------------------------------------
__global__ __launch_bounds__(256) void k_transpose_f16(
    const float* __restrict__ src, f16* __restrict__ dhi,
    const int K, const int N)
{
  __shared__ float tile[32][33];
  const int n0 = blockIdx.x * 32, k0 = blockIdx.y * 32;
  const int tx = threadIdx.x & 31, ty = threadIdx.x >> 5;
  #pragma unroll
  for (int ii = 0; ii < 4; ++ii){
    const int k = k0 + ty + ii*8, n = n0 + tx;
    float v = (n < N) ? src[(size_t)k * N + n] : 0.0f;
    tile[ty + ii*8][tx] = v;
  }
  __syncthreads();
  #pragma unroll
  for (int ii = 0; ii < 4; ++ii){
    const int n = n0 + ty + ii*8, k = k0 + tx;
    dhi[(size_t)n * K + k] = (f16)tile[tx][ty + ii*8];
  }
}

__global__ void k_f32_to_bf16(const float* __restrict__ src,
                              unsigned short* __restrict__ dst, const int n4)
{
  const int i = blockIdx.x * 256 + threadIdx.x;
  if (i < n4){
    f32x4v v = *reinterpret_cast<const f32x4v*>(src + (size_t)i * 4);
    u16x4 o;
    #pragma unroll
    for (int j = 0; j < 4; ++j) o[j] = f2bf(v[j]);
    *reinterpret_cast<u16x4*>(dst + (size_t)i * 4) = o;
  }
}

// pack cell1 conv weights into u32 pairs: wp32[(icg*3 + w)*128 + gc],
// u32 = tap(2w) | tap(2w+1)<<16, tap order [ch0,ch1,ch2,cx0,cx1,cx2] (bf16).
__global__ void k_pack_cellw(const float* __restrict__ chw,
                             const float* __restrict__ cxw,
                             unsigned int* __restrict__ wp32)
{
  const int i = blockIdx.x * 256 + threadIdx.x;   // i = gc*32 + icg
  if (i < 128 * 32){
    const int gc = i >> 5, icg = i & 31;
    unsigned short tap[6];
    #pragma unroll
    for (int k = 0; k < 3; ++k){
      tap[k]   = f2bf(chw[i*3 + k]);
      tap[3+k] = f2bf(cxw[i*3 + k]);
    }
    #pragma unroll
    for (int w = 0; w < 3; ++w)
      wp32[(icg*3 + w)*128 + gc] =
          (unsigned int)tap[2*w] | ((unsigned int)tap[2*w+1] << 16);
  }
}

// ---------------------------------------------------------------------------
// Layer-0 ConvLSTM for ALL 64 steps. Block=(b,row).
// h_lds padded 264 (+132 per ih group): conflict-free b128 broadcasts.
// ---------------------------------------------------------------------------
__global__ __launch_bounds__(256) void k_cell0(
    const float* __restrict__ x_flat,
    const float* __restrict__ h0, const float* __restrict__ c0,
    const float* __restrict__ cxw, const float* __restrict__ cxb,
    const float* __restrict__ chw, const float* __restrict__ chb,
    f16* __restrict__ hrawHi, f16* __restrict__ hrawLo)     // [T][B][2048]
{
  const int b = blockIdx.x >> 3, row = blockIdx.x & 7;
  const int tid = threadIdx.x;
  __shared__ float h_lds[264];
  __shared__ float x_lds[8];
  __shared__ float P[128][2][9];
  const int gc = tid >> 1, ih = tid & 1;
  float wh[16][3];
  #pragma unroll
  for (int icl = 0; icl < 16; ++icl)
    #pragma unroll
    for (int k = 0; k < 3; ++k)
      wh[icl][k] = chw[(gc*32 + ih*16 + icl)*3 + k];
  const float wx0 = cxw[gc*3+0], wx1 = cxw[gc*3+1], wx2 = cxw[gc*3+2];
  const float bsum = cxb[gc] + chb[gc];
  const int ic = tid >> 3, col = tid & 7;
  const size_t dg = (size_t)b*2048 + row*256 + tid;
  const int wofs = tid + ((tid >> 7) << 2);    // padded write index
  const int hbase = ih * 132;                  // padded read base per ih group
  float c_reg = c0[dg];
  h_lds[wofs] = h0[dg];
  float xnext = (tid < 8) ? x_flat[((size_t)b*64 + 0)*64 + row*8 + tid] : 0.f;
  __syncthreads();
  for (int t = 0; t < 64; ++t){
    if (tid < 8) x_lds[tid] = xnext;
    __syncthreads();
    if (t < 63 && tid < 8)
      xnext = x_flat[((size_t)b*64 + t + 1)*64 + row*8 + tid];
    float g8[8];
    #pragma unroll
    for (int c2 = 0; c2 < 8; ++c2) g8[c2] = 0.f;
    #pragma unroll
    for (int icl = 0; icl < 16; ++icl){
      const float* hb = &h_lds[icl*8 + hbase];
      f32x4v hv0 = *reinterpret_cast<const f32x4v*>(hb);
      f32x4v hv1 = *reinterpret_cast<const f32x4v*>(hb + 4);
      const float hv[8] = {hv0[0],hv0[1],hv0[2],hv0[3],hv1[0],hv1[1],hv1[2],hv1[3]};
      #pragma unroll
      for (int c2 = 0; c2 < 8; ++c2){
        float s = hv[c2] * wh[icl][1];
        if (c2 > 0) s += hv[c2-1] * wh[icl][0];
        if (c2 < 7) s += hv[c2+1] * wh[icl][2];
        g8[c2] += s;
      }
    }
    if (ih == 0){
      #pragma unroll
      for (int c2 = 0; c2 < 8; ++c2){
        float s = x_lds[c2] * wx1 + bsum;
        if (c2 > 0) s += x_lds[c2-1] * wx0;
        if (c2 < 7) s += x_lds[c2+1] * wx2;
        g8[c2] += s;
      }
    }
    #pragma unroll
    for (int c2 = 0; c2 < 8; ++c2) P[gc][ih][c2] = g8[c2];
    __syncthreads();
    const float ipre = P[ic   ][0][col] + P[ic   ][1][col];
    const float fpre = P[ic+32][0][col] + P[ic+32][1][col];
    const float opre = P[ic+64][0][col] + P[ic+64][1][col];
    const float gpre = P[ic+96][0][col] + P[ic+96][1][col];
    const float cn = sigmoidf_(fpre)*c_reg + sigmoidf_(ipre)*tanhf(gpre);
    c_reg = cn;
    const float hn = sigmoidf_(opre)*tanhf(cn);
    const f16 hh = (f16)hn;
    hrawHi[((size_t)t*128 + b)*2048 + row*256 + tid] = hh;
    hrawLo[((size_t)t*128 + b)*2048 + row*256 + tid] = (f16)(hn - (float)hh);
    __syncthreads();
    h_lds[wofs] = hn;
  }
}

// ---------------------------------------------------------------------------
// Layer-1 ConvLSTM for ALL 64 steps. Weights in LDS (packed u32,
// conflict-free [icg*3+w][gc]); padded h/x LDS; no weight VGPR pressure.
// ---------------------------------------------------------------------------
__global__ __launch_bounds__(256) void k_cell1_all(
    const f16* __restrict__ r0Hi, const f16* __restrict__ r0Lo,
    const float* __restrict__ h0s, const float* __restrict__ c0s,
    const unsigned int* __restrict__ wp32,     // [(icg*3+w)*128+gc]
    const float* __restrict__ cxb, const float* __restrict__ chb,
    f16* __restrict__ hrw1Hi, f16* __restrict__ hrw1Lo)            // [T][B][2048]
{
  const int b = blockIdx.x >> 3, row = blockIdx.x & 7;
  const int tid = threadIdx.x;
  __shared__ float x_lds[264];
  __shared__ float h_lds[264];
  __shared__ float P[128][2][9];
  __shared__ unsigned int wlds32[96*128];      // 48 KB
  const int gc = tid >> 1, ih = tid & 1;
  for (int i = tid; i < 96*128; i += 256) wlds32[i] = wp32[i];
  const size_t dg = (size_t)b*2048 + row*256 + tid;
  const int ic = tid >> 3, col = tid & 7;
  const float bi = cxb[ic]    + chb[ic];
  const float bf = cxb[ic+32] + chb[ic+32];
  const float bo = cxb[ic+64] + chb[ic+64];
  const float bg = cxb[ic+96] + chb[ic+96];
  const int wofs = tid + ((tid >> 7) << 2);
  const int hbase = ih * 132;
  float c_reg = c0s[dg];
  h_lds[wofs] = h0s[dg];
  float xnext = (float)r0Hi[dg] + (float)r0Lo[dg];
  __syncthreads();
  for (int t = 0; t < 64; ++t){
    x_lds[wofs] = xnext;
    __syncthreads();
    if (t < 63)
      xnext = (float)r0Hi[(size_t)(t+1)*BD + dg] + (float)r0Lo[(size_t)(t+1)*BD + dg];
    {
      float g8[8];
      #pragma unroll
      for (int c2 = 0; c2 < 8; ++c2) g8[c2] = 0.f;
      #pragma unroll
      for (int icl = 0; icl < 16; ++icl){
        const int icg = ih*16 + icl;
        const float* hb = &h_lds[icl*8 + hbase];
        const float* xb = &x_lds[icl*8 + hbase];
        f32x4v hv0 = *reinterpret_cast<const f32x4v*>(hb);
        f32x4v hv1 = *reinterpret_cast<const f32x4v*>(hb + 4);
        f32x4v xv0 = *reinterpret_cast<const f32x4v*>(xb);
        f32x4v xv1 = *reinterpret_cast<const f32x4v*>(xb + 4);
        const float hv[8] = {hv0[0],hv0[1],hv0[2],hv0[3],hv1[0],hv1[1],hv1[2],hv1[3]};
        const float xv[8] = {xv0[0],xv0[1],xv0[2],xv0[3],xv1[0],xv1[1],xv1[2],xv1[3]};
        const unsigned int* wq = &wlds32[icg*3*128 + gc];
        const unsigned int w0 = wq[0], w1 = wq[128], w2 = wq[256];
        const float wh0 = bf2f((unsigned short)(w0 & 0xffffu));
        const float wh1 = bf2f((unsigned short)(w0 >> 16));
        const float wh2 = bf2f((unsigned short)(w1 & 0xffffu));
        const float wx0 = bf2f((unsigned short)(w1 >> 16));
        const float wx1 = bf2f((unsigned short)(w2 & 0xffffu));
        const float wx2 = bf2f((unsigned short)(w2 >> 16));
        #pragma unroll
        for (int c2 = 0; c2 < 8; ++c2){
          float s = hv[c2]*wh1 + xv[c2]*wx1;
          if (c2 > 0) s += hv[c2-1]*wh0 + xv[c2-1]*wx0;
          if (c2 < 7) s += hv[c2+1]*wh2 + xv[c2+1]*wx2;
          g8[c2] += s;
        }
      }
      #pragma unroll
      for (int c2 = 0; c2 < 8; ++c2) P[gc][ih][c2] = g8[c2];
    }
    __syncthreads();
    {
      const float ipre = P[ic   ][0][col] + P[ic   ][1][col] + bi;
      const float fpre = P[ic+32][0][col] + P[ic+32][1][col] + bf;
      const float opre = P[ic+64][0][col] + P[ic+64][1][col] + bo;
      const float gpre = P[ic+96][0][col] + P[ic+96][1][col] + bg;
      const float cn = sigmoidf_(fpre)*c_reg + sigmoidf_(ipre)*tanhf(gpre);
      c_reg = cn;
      const float hraw = sigmoidf_(opre)*tanhf(cn);
      const f16 hh = (f16)hraw;
      hrw1Hi[(size_t)t*BD + dg] = hh;
      hrw1Lo[(size_t)t*BD + dg] = (f16)(hraw - (float)hh);
      __syncthreads();           // all P reads done before next iter overwrites
      h_lds[wofs] = hraw;
    }
  }
}

// ---------------------------------------------------------------------------
// Batched inter-attention (both layers, all t): block (b, t), 8 waves x 16
// encoder rows, online softmax, deterministic 8-way LDS combine.
// ---------------------------------------------------------------------------
__global__ __launch_bounds__(512) void k_inter_b(
    const unsigned short* __restrict__ encBf,
    const f16* __restrict__ stHi, const f16* __restrict__ stLo,   // [T][B][2048]
    f16* __restrict__ ctxHi, f16* __restrict__ ctxLo)
{
  const int b = blockIdx.x;
  const size_t so = (size_t)blockIdx.y * BD + (size_t)b * 2048;
  const int tid = threadIdx.x;
  const int lane = tid & 63, wv = tid >> 6;
  __shared__ float wav[8][2048];
  __shared__ float wm[8], wl[8];
  float sv[32], av[32];
  #pragma unroll
  for (int p = 0; p < 4; ++p){
    const int d = (p*64 + lane)*8;
    f16x8 hh = *reinterpret_cast<const f16x8*>(stHi + so + d);
    f16x8 ll = *reinterpret_cast<const f16x8*>(stLo + so + d);
    #pragma unroll
    for (int j = 0; j < 8; ++j){ sv[p*8+j] = (float)hh[j] + (float)ll[j]; av[p*8+j] = 0.f; }
  }
  float m = -INFINITY, l = 0.f;
  const int s0 = wv*16;
  for (int r = 0; r < 16; ++r){
    const unsigned short* er = encBf + ((size_t)b*128 + s0 + r)*2048;
    float ef[32];
    float dot = 0.f;
    #pragma unroll
    for (int p = 0; p < 4; ++p){
      u16x8 ev = *reinterpret_cast<const u16x8*>(er + (p*64 + lane)*8);
      #pragma unroll
      for (int j = 0; j < 8; ++j){ const float e = bf2f(ev[j]); ef[p*8+j] = e; dot += e * sv[p*8+j]; }
    }
    #pragma unroll
    for (int off = 1; off < 64; off <<= 1) dot += __shfl_xor(dot, off);
    if (dot > m){
      const float scf = __expf(m - dot);
      l *= scf;
      #pragma unroll
      for (int q = 0; q < 32; ++q) av[q] *= scf;
      m = dot;
    }
    const float pp = __expf(dot - m);
    l += pp;
    #pragma unroll
    for (int q = 0; q < 32; ++q) av[q] += pp * ef[q];
  }
  #pragma unroll
  for (int p = 0; p < 4; ++p){
    const int d = (p*64 + lane)*8;
    f32x4v v0, v1;
    #pragma unroll
    for (int j = 0; j < 4; ++j){ v0[j] = av[p*8+j]; v1[j] = av[p*8+4+j]; }
    *reinterpret_cast<f32x4v*>(&wav[wv][d]) = v0;
    *reinterpret_cast<f32x4v*>(&wav[wv][d+4]) = v1;
  }
  if (lane == 0){ wm[wv] = m; wl[wv] = l; }
  __syncthreads();
  float M = wm[0];
  #pragma unroll
  for (int i = 1; i < 8; ++i) M = fmaxf(M, wm[i]);
  float U[8];
  float L = 0.f;
  #pragma unroll
  for (int i = 0; i < 8; ++i){ U[i] = __expf(wm[i] - M); L += wl[i] * U[i]; }
  const float Linv = 1.f / L;
  const int d0 = tid * 4;
  float acc[4] = {0.f, 0.f, 0.f, 0.f};
  #pragma unroll
  for (int w = 0; w < 8; ++w){
    f32x4v v = *reinterpret_cast<const f32x4v*>(&wav[w][d0]);
    #pragma unroll
    for (int j = 0; j < 4; ++j) acc[j] += U[w] * v[j];
  }
  f16x4 hh, ll;
  #pragma unroll
  for (int j = 0; j < 4; ++j){
    const float v = acc[j] * Linv;
    hh[j] = (f16)v;
    ll[j] = (f16)(v - (float)hh[j]);
  }
  *reinterpret_cast<f16x4*>(ctxHi + so + d0) = hh;
  *reinterpret_cast<f16x4*>(ctxLo + so + d0) = ll;
}

// ---------------------------------------------------------------------------
// Batched full-K ia GEMM (all t): p[t] = tanh([A0|A1]@W + bias), f16 hi/lo.
// Grid (32 nt, 64 t). K=4096, f16 2-pass MFMA, global_load_lds double-buffer.
// ---------------------------------------------------------------------------
__global__ __launch_bounds__(256, 2) void k_gemm_full(
    const f16* __restrict__ a0Hi, const f16* __restrict__ a0Lo,
    const f16* __restrict__ a1Hi, const f16* __restrict__ a1Lo,
    const f16* __restrict__ wHp, const float* __restrict__ bias,
    f16* __restrict__ outHi, f16* __restrict__ outLo)
{
  const int nt = blockIdx.x, t = blockIdx.y;
  const size_t tb = (size_t)t * BD;
  const int tid = threadIdx.x;
  const int lane = tid & 63, wv = tid >> 6;
  __shared__ __align__(16) char lds[81920];
  const f16* wH = wHp + (size_t)(nt*64)*4096;

  auto stage = [&](int buf, int ki){
    char* lb = lds + buf*40960;
    const f16* aH = ((ki < 32) ? a0Hi : a1Hi) + tb;
    const f16* aL = ((ki < 32) ? a0Lo : a1Lo) + tb;
    const int ke = (ki & 31) * 64;
    #pragma unroll
    for (int i = 0; i < 4; ++i){
      const int c = i*256 + tid, row = c >> 3;
      const int srcb = ((c & 7)*16) ^ ((row & 7) << 4);
      g2l16((const char*)(aH + (size_t)row*2048 + ke) + srcb, lb + c*16);
      g2l16((const char*)(aL + (size_t)row*2048 + ke) + srcb, lb + 16384 + c*16);
    }
    #pragma unroll
    for (int i = 0; i < 2; ++i){
      const int c = i*256 + tid, row = c >> 3;
      const int srcb = ((c & 7)*16) ^ ((row & 7) << 4);
      g2l16((const char*)(wH + (size_t)row*4096 + ki*64) + srcb, lb + 32768 + c*16);
    }
  };

  f32x16 acc0, acc1;
  #pragma unroll
  for (int r = 0; r < 16; ++r){ acc0[r] = 0.f; acc1[r] = 0.f; }
  const int rA = wv*32 + (lane & 31);
  const int kb = lane >> 5;
  const int rB0 = lane & 31;
  const int aswz = (rA & 7) << 4;
  const int bswz = (rB0 & 7) << 4;

  stage(0, 0);
  __syncthreads();
  for (int ki = 0; ki < 64; ++ki){
    const int buf = ki & 1;
    if (ki < 63) stage(buf ^ 1, ki + 1);
    const char* lb = lds + buf*40960;
    #pragma unroll
    for (int s = 0; s < 4; ++s){
      const int cb = s*32 + kb*16;
      f16x8 ah  = *reinterpret_cast<const f16x8*>(lb + rA*128 + (cb ^ aswz));
      f16x8 al  = *reinterpret_cast<const f16x8*>(lb + 16384 + rA*128 + (cb ^ aswz));
      f16x8 b0h = *reinterpret_cast<const f16x8*>(lb + 32768 + rB0*128 + (cb ^ bswz));
      f16x8 b1h = *reinterpret_cast<const f16x8*>(lb + 32768 + 4096 + rB0*128 + (cb ^ bswz));
      acc0 = __builtin_amdgcn_mfma_f32_32x32x16_f16(ah, b0h, acc0, 0, 0, 0);
      acc1 = __builtin_amdgcn_mfma_f32_32x32x16_f16(ah, b1h, acc1, 0, 0, 0);
      acc0 = __builtin_amdgcn_mfma_f32_32x32x16_f16(al, b0h, acc0, 0, 0, 0);
      acc1 = __builtin_amdgcn_mfma_f32_32x32x16_f16(al, b1h, acc1, 0, 0, 0);
    }
    __syncthreads();
  }

  const int col0 = nt*64 + (lane & 31);
  const float b0 = bias[col0], b1 = bias[col0 + 32];
  const int rowBase = wv*32 + 4*kb;
  #pragma unroll
  for (int r = 0; r < 16; ++r){
    const int rr = rowBase + (r & 3) + 8*(r >> 2);
    const size_t o = tb + (size_t)rr*2048 + col0;
    const float p = tanhf(acc0[r] + b0);
    const float q = tanhf(acc1[r] + b1);
    const f16 ph = (f16)p, qh = (f16)q;
    outHi[o]      = ph;  outLo[o]      = (f16)(p - (float)ph);
    outHi[o + 32] = qh;  outLo[o + 32] = (f16)(q - (float)qh);
  }
}

// ---------------------------------------------------------------------------
// Batched sa GEMM (all t): A = p hi/lo, W = [Wlow^T|Wup^T] ([4096][2048]).
// nt<32 -> Y (f32, raw); nt>=32 -> G (f16). Grid (64 nt, 64 t), K=2048.
// ---------------------------------------------------------------------------
__global__ __launch_bounds__(256, 2) void k_gemm_full2(
    const f16* __restrict__ aHi, const f16* __restrict__ aLo,   // [T][B][2048]
    const f16* __restrict__ wSp,                                // [4096][2048]
    float* __restrict__ Y, f16* __restrict__ G)                 // [T][B][2048]
{
  const int nt = blockIdx.x, t = blockIdx.y;
  const size_t tb = (size_t)t * BD;
  const int tid = threadIdx.x;
  const int lane = tid & 63, wv = tid >> 6;
  __shared__ __align__(16) char lds[81920];
  const f16* wH = wSp + (size_t)(nt*64)*2048;
  const f16* aH = aHi + tb;
  const f16* aL = aLo + tb;

  auto stage = [&](int buf, int ki){
    char* lb = lds + buf*40960;
    const int ke = ki*64;
    #pragma unroll
    for (int i = 0; i < 4; ++i){
      const int c = i*256 + tid, row = c >> 3;
      const int srcb = ((c & 7)*16) ^ ((row & 7) << 4);
      g2l16((const char*)(aH + (size_t)row*2048 + ke) + srcb, lb + c*16);
      g2l16((const char*)(aL + (size_t)row*2048 + ke) + srcb, lb + 16384 + c*16);
    }
    #pragma unroll
    for (int i = 0; i < 2; ++i){
      const int c = i*256 + tid, row = c >> 3;
      const int srcb = ((c & 7)*16) ^ ((row & 7) << 4);
      g2l16((const char*)(wH + (size_t)row*2048 + ke) + srcb, lb + 32768 + c*16);
    }
  };

  f32x16 acc0, acc1;
  #pragma unroll
  for (int r = 0; r < 16; ++r){ acc0[r] = 0.f; acc1[r] = 0.f; }
  const int rA = wv*32 + (lane & 31);
  const int kb = lane >> 5;
  const int rB0 = lane & 31;
  const int aswz = (rA & 7) << 4;
  const int bswz = (rB0 & 7) << 4;

  stage(0, 0);
  __syncthreads();
  for (int ki = 0; ki < 32; ++ki){
    const int buf = ki & 1;
    if (ki < 31) stage(buf ^ 1, ki + 1);
    const char* lb = lds + buf*40960;
    #pragma unroll
    for (int s = 0; s < 4; ++s){
      const int cb = s*32 + kb*16;
      f16x8 ah  = *reinterpret_cast<const f16x8*>(lb + rA*128 + (cb ^ aswz));
      f16x8 al  = *reinterpret_cast<const f16x8*>(lb + 16384 + rA*128 + (cb ^ aswz));
      f16x8 b0h = *reinterpret_cast<const f16x8*>(lb + 32768 + rB0*128 + (cb ^ bswz));
      f16x8 b1h = *reinterpret_cast<const f16x8*>(lb + 32768 + 4096 + rB0*128 + (cb ^ bswz));
      acc0 = __builtin_amdgcn_mfma_f32_32x32x16_f16(ah, b0h, acc0, 0, 0, 0);
      acc1 = __builtin_amdgcn_mfma_f32_32x32x16_f16(ah, b1h, acc1, 0, 0, 0);
      acc0 = __builtin_amdgcn_mfma_f32_32x32x16_f16(al, b0h, acc0, 0, 0, 0);
      acc1 = __builtin_amdgcn_mfma_f32_32x32x16_f16(al, b1h, acc1, 0, 0, 0);
    }
    __syncthreads();
  }

  const int col0 = nt*64 + (lane & 31);
  const int rowBase = wv*32 + 4*kb;
  if (nt < 32){
    float* yp = Y + tb + col0;
    #pragma unroll
    for (int r = 0; r < 16; ++r){
      const int rr = rowBase + (r & 3) + 8*(r >> 2);
      yp[(size_t)rr*2048]      = acc0[r];
      yp[(size_t)rr*2048 + 32] = acc1[r];
    }
  } else {
    f16* gp = G + tb + (col0 - 2048);
    #pragma unroll
    for (int r = 0; r < 16; ++r){
      const int rr = rowBase + (r & 3) + 8*(r >> 2);
      gp[(size_t)rr*2048]      = (f16)acc0[r];
      gp[(size_t)rr*2048 + 32] = (f16)acc1[r];
    }
  }
}

// ---------------------------------------------------------------------------
// Self-attention refine chain (persistent over t). Block per b, 512 threads.
// ---------------------------------------------------------------------------
__global__ __launch_bounds__(512) void k_selfchain(
    const f16* __restrict__ pHi, const f16* __restrict__ pLo,   // [T][B][2048]
    const float* __restrict__ Y, const f16* __restrict__ G,     // [T][B][2048]
    const float* __restrict__ bias,
    f16* __restrict__ rHi, f16* __restrict__ rLo)               // [T][B][2048]
{
  const int b = blockIdx.x;
  const int tid = threadIdx.x, lane = tid & 63, wv = tid >> 6;   // 8 waves
  __shared__ float sc[64];
  __shared__ float a_lds[64];
  const int d0 = tid * 4;
  f32x4v bb = *reinterpret_cast<const f32x4v*>(bias + d0);
  for (int t = 0; t < 64; ++t){
    const size_t pb = ((size_t)t*128 + b)*2048;
    if (t > 0){
      float hreg[32];
      #pragma unroll
      for (int jj = 0; jj < 4; ++jj){
        const int d = (jj*64 + lane)*8;
        f16x8 h8 = *reinterpret_cast<const f16x8*>(pHi + pb + d);
        f16x8 l8 = *reinterpret_cast<const f16x8*>(pLo + pb + d);
        #pragma unroll
        for (int j = 0; j < 8; ++j) hreg[jj*8+j] = (float)h8[j] + (float)l8[j];
      }
      for (int i = wv; i < t; i += 8){
        const f16* rh = rHi + ((size_t)i*128 + b)*2048;
        const f16* rl = rLo + ((size_t)i*128 + b)*2048;
        float dot = 0.f;
        #pragma unroll
        for (int jj = 0; jj < 4; ++jj){
          const int d = (jj*64 + lane)*8;
          f16x8 h8 = *reinterpret_cast<const f16x8*>(rh + d);
          f16x8 l8 = *reinterpret_cast<const f16x8*>(rl + d);
          #pragma unroll
          for (int j = 0; j < 8; ++j)
            dot += ((float)h8[j] + (float)l8[j]) * hreg[jj*8+j];
        }
        #pragma unroll
        for (int off = 1; off < 64; off <<= 1) dot += __shfl_xor(dot, off);
        if (lane == 0) sc[i] = dot;
      }
      __syncthreads();
      if (tid < 64){
        const float s = (tid < t) ? sc[tid] : -INFINITY;
        float mm = s;
        #pragma unroll
        for (int off = 1; off < 64; off <<= 1) mm = fmaxf(mm, __shfl_xor(mm, off));
        const float e = (tid < t) ? __expf(s - mm) : 0.f;
        float sum = e;
        #pragma unroll
        for (int off = 1; off < 64; off <<= 1) sum += __shfl_xor(sum, off);
        a_lds[tid] = e / sum;
      }
      __syncthreads();
    }
    float y[4];
    {
      f32x4v yv = *reinterpret_cast<const f32x4v*>(Y + (size_t)t*BD + (size_t)b*2048 + d0);
      #pragma unroll
      for (int j = 0; j < 4; ++j) y[j] = yv[j] + bb[j];
    }
    if (t > 0){
      for (int i = 0; i < t; ++i){
        const float a = a_lds[i];
        f16x4 g4 = *reinterpret_cast<const f16x4*>(G + ((size_t)i*128 + b)*2048 + d0);
        #pragma unroll
        for (int j = 0; j < 4; ++j) y[j] += a * (float)g4[j];
      }
    }
    f16x4 hh, ll;
    #pragma unroll
    for (int j = 0; j < 4; ++j){
      const float v = tanhf(y[j]);
      hh[j] = (f16)v;
      ll[j] = (f16)(v - (float)hh[j]);
    }
    *reinterpret_cast<f16x4*>(rHi + pb + d0) = hh;
    *reinterpret_cast<f16x4*>(rLo + pb + d0) = ll;
    __syncthreads();   // r[t] stores drained before t+1 scores read them
  }
}

// ---------------------------------------------------------------------------
// Head stage 1: z1 = relu(r1(8192x2048) @ hw1 + hb1), f16 2-pass MFMA
// ---------------------------------------------------------------------------
__global__ __launch_bounds__(256) void k_headgemm(
    const f16* __restrict__ aHi, const f16* __restrict__ aLo,
    const f16* __restrict__ w1H,   // [224][2048]
    const float* __restrict__ hb1,
    float* __restrict__ z1)        // [8192][224]
{
  const int mb = blockIdx.x;
  const int nt = blockIdx.y;
  const int lane = threadIdx.x & 63, wv = threadIdx.x >> 6;
  const int rowA = mb*128 + wv*32 + (lane & 31);
  const int kb = lane >> 5;
  const int n = nt*32 + (lane & 31);
  const f16* pAH = aHi + (size_t)rowA*2048 + kb*8;
  const f16* pAL = aLo + (size_t)rowA*2048 + kb*8;
  const f16* pBH = w1H + (size_t)n*2048 + kb*8;
  f32x16 acc;
  #pragma unroll
  for (int r = 0; r < 16; ++r) acc[r] = 0.f;
  #pragma unroll 4
  for (int s = 0; s < 128; ++s){
    f16x8 ah = *reinterpret_cast<const f16x8*>(pAH + s*16);
    f16x8 al = *reinterpret_cast<const f16x8*>(pAL + s*16);
    f16x8 bh = *reinterpret_cast<const f16x8*>(pBH + s*16);
    acc = __builtin_amdgcn_mfma_f32_32x32x16_f16(ah, bh, acc, 0, 0, 0);
    acc = __builtin_amdgcn_mfma_f32_32x32x16_f16(al, bh, acc, 0, 0, 0);
  }
  const float bias = (n < 200) ? hb1[n] : 0.f;
  const int rowBase = mb*128 + wv*32 + 4*kb;
  #pragma unroll
  for (int r = 0; r < 16; ++r){
    const int rr = rowBase + (r & 3) + 8*(r >> 2);
    z1[(size_t)rr*224 + n] = fmaxf(acc[r] + bias, 0.f);
  }
}

// Head stage 2
__global__ __launch_bounds__(256) void k_head2(
    const float* __restrict__ z1,
    const float* __restrict__ hw2, const float* __restrict__ hb2,
    const float* __restrict__ hw3, const float* __restrict__ hb3,
    float* __restrict__ out)
{
  const int r0 = blockIdx.x * 64;
  const int tid = threadIdx.x;
  __shared__ float zl[64][200];
  __shared__ float z2[64][50];
  for (int i = tid; i < 64*200; i += 256){
    const int r = i / 200, n = i % 200;
    zl[r][n] = z1[(size_t)(r0 + r)*224 + n];
  }
  __syncthreads();
  for (int i = tid; i < 64*50; i += 256){
    const int r = i / 50, n = i % 50;
    float s = hb2[n];
    for (int k = 0; k < 200; ++k) s += zl[r][k] * hw2[k*50 + n];
    z2[r][n] = fmaxf(s, 0.f);
  }
  __syncthreads();
  for (int i = tid; i < 128; i += 256){
    const int r = i >> 1, c = i & 1;
    float s = hb3[c];
    for (int k = 0; k < 50; ++k) s += z2[r][k] * hw3[k*2 + c];
    const int rg = r0 + r;
    const int tt = rg >> 7, b = rg & 127;
    out[(size_t)b*128 + tt*2 + c] = s;
  }
}

// ---------------------------------------------------------------------------
extern "C" void kernel_launch(void* const* d_in, const int* in_sizes, int n_in,
                              void* d_out, int out_size, void* d_ws, size_t ws_size,
                              hipStream_t stream)
{
  (void)in_sizes; (void)n_in; (void)out_size; (void)ws_size;
  const float* x_flat = (const float*)d_in[0];
  const float* enc    = (const float*)d_in[1];
  const float* h0     = (const float*)d_in[2];
  const float* c0     = (const float*)d_in[3];
  const float* cx_w0  = (const float*)d_in[4];
  const float* cx_b0  = (const float*)d_in[5];
  const float* ch_w0  = (const float*)d_in[6];
  const float* ch_b0  = (const float*)d_in[7];
  const float* cx_w1  = (const float*)d_in[8];
  const float* cx_b1  = (const float*)d_in[9];
  const float* ch_w1  = (const float*)d_in[10];
  const float* ch_b1  = (const float*)d_in[11];
  const float* ia_w0  = (const float*)d_in[12];
  const float* ia_b0  = (const float*)d_in[13];
  const float* sa_w0  = (const float*)d_in[14];
  const float* sa_b0  = (const float*)d_in[15];
  const float* ia_w1  = (const float*)d_in[16];
  const float* ia_b1  = (const float*)d_in[17];
  const float* sa_w1  = (const float*)d_in[18];
  const float* sa_b1  = (const float*)d_in[19];
  const float* hw1    = (const float*)d_in[20];
  const float* hb1    = (const float*)d_in[21];
  const float* hw2    = (const float*)d_in[22];
  const float* hb2    = (const float*)d_in[23];
  const float* hw3    = (const float*)d_in[24];
  const float* hb3    = (const float*)d_in[25];
  float* out = (float*)d_out;

  char* ws = (char*)d_ws;
  size_t off = 0;
  auto alloc = [&](size_t bytes) -> char* {
    char* p = ws + off;
    off += (bytes + 255) & ~(size_t)255;
    return p;
  };
  const size_t WPLANE = (size_t)2048*4096*2;   // 16 MiB
  const size_t TPLANE = (size_t)64*BD*2;       // 32 MiB, [T][B][D] f16
  f16* wIa0 = (f16*)alloc(WPLANE);
  f16* wSa0 = (f16*)alloc(WPLANE);   // [4096][2048]: Wlow^T rows 0..2047, Wup^T rows 2048..
  f16* wIa1 = (f16*)alloc(WPLANE);
  f16* wSa1 = (f16*)alloc(WPLANE);
  f16* w1H  = (f16*)alloc((size_t)224*2048*2);
  unsigned short* encBf = (unsigned short*)alloc((size_t)128*128*2048*2);
  f16* S1 = (f16*)alloc(TPLANE);
  f16* S2 = (f16*)alloc(TPLANE);
  f16* S3 = (f16*)alloc(TPLANE);
  f16* S4 = (f16*)alloc(TPLANE);
  f16* S5 = (f16*)alloc(TPLANE);
  f16* S6 = (f16*)alloc(TPLANE);
  f16* S7 = (f16*)alloc(TPLANE);
  f16* S8 = (f16*)alloc(TPLANE);
  unsigned int* wpack1 = (unsigned int*)alloc((size_t)96*128*4);
  // total ws ~= 385 MiB. Alias names (lifetimes verified disjoint):
  f16*  hr0AHi = S1;  f16* hr0ALo = S2;
  f16*  ctx0Hi = S3;  f16* ctx0Lo = S4;
  f16*  p0Hi   = S5;  f16* p0Lo   = S6;
  float* Y0 = (float*)S1;                    // 64 MiB over S1+S2 (contiguous)
  f16*  G0  = S3;
  f16*  r0Hi = S7;    f16* r0Lo   = S8;
  f16*  hrw1Hi = S5;  f16* hrw1Lo = S6;
  f16*  ctx1Hi = S1;  f16* ctx1Lo = S2;
  f16*  p1Hi = S7;    f16* p1Lo   = S8;
  float* Y1 = (float*)S1;                    // 64 MiB over S1+S2
  f16*  G1  = S4;
  f16*  r1Hi = S5;    f16* r1Lo   = S3;
  float* z1 = (float*)wSa0;                  // head scratch (wSa0 dead by then)

  // ---- prologue -----------------------------------------------------------
  k_transpose_f16<<<dim3(64,128),256,0,stream>>>(ia_w0, wIa0, 4096, 2048);
  k_transpose_f16<<<dim3(64,128),256,0,stream>>>(ia_w1, wIa1, 4096, 2048);
  k_transpose_f16<<<dim3(64,64),256,0,stream>>>(sa_w0, wSa0, 2048, 2048);
  k_transpose_f16<<<dim3(64,64),256,0,stream>>>(sa_w0 + (size_t)2048*2048,
                                                wSa0 + (size_t)2048*2048, 2048, 2048);
  k_transpose_f16<<<dim3(64,64),256,0,stream>>>(sa_w1, wSa1, 2048, 2048);
  k_transpose_f16<<<dim3(64,64),256,0,stream>>>(sa_w1 + (size_t)2048*2048,
                                                wSa1 + (size_t)2048*2048, 2048, 2048);
  k_transpose_f16<<<dim3(7,64),256,0,stream>>>(hw1, w1H, 2048, 200);
  k_f32_to_bf16<<<(128*128*2048/4 + 255)/256, 256, 0, stream>>>(enc, encBf, 128*128*2048/4);
  k_pack_cellw<<<16,256,0,stream>>>(ch_w1, cx_w1, wpack1);

  // ---- layer 0 (fully batched + one persistent chain) ---------------------
  k_cell0<<<1024,256,0,stream>>>(x_flat, h0, c0, cx_w0, cx_b0, ch_w0, ch_b0,
                                 hr0AHi, hr0ALo);
  k_inter_b<<<dim3(128,64),512,0,stream>>>(encBf, hr0AHi, hr0ALo, ctx0Hi, ctx0Lo);
  k_gemm_full<<<dim3(32,64),256,0,stream>>>(hr0AHi, hr0ALo, ctx0Hi, ctx0Lo,
                                            wIa0, ia_b0, p0Hi, p0Lo);
  k_gemm_full2<<<dim3(64,64),256,0,stream>>>(p0Hi, p0Lo, wSa0, Y0, G0);
  k_selfchain<<<128,512,0,stream>>>(p0Hi, p0Lo, Y0, G0, sa_b0, r0Hi, r0Lo);

  // ---- layer 1 (persistent cell + fully batched + one persistent chain) ---
  k_cell1_all<<<1024,256,0,stream>>>(r0Hi, r0Lo,
                                     h0 + (size_t)128*2048, c0 + (size_t)128*2048,
                                     wpack1, cx_b1, ch_b1, hrw1Hi, hrw1Lo);
  k_inter_b<<<dim3(128,64),512,0,stream>>>(encBf, hrw1Hi, hrw1Lo, ctx1Hi, ctx1Lo);
  k_gemm_full<<<dim3(32,64),256,0,stream>>>(hrw1Hi, hrw1Lo, ctx1Hi, ctx1Lo,
                                            wIa1, ia_b1, p1Hi, p1Lo);
  k_gemm_full2<<<dim3(64,64),256,0,stream>>>(p1Hi, p1Lo, wSa1, Y1, G1);
  k_selfchain<<<128,512,0,stream>>>(p1Hi, p1Lo, Y1, G1, sa_b1, r1Hi, r1Lo);

  // ---- head (batched over all t,b) ----------------------------------------
  k_headgemm<<<dim3(64,7),256,0,stream>>>(r1Hi, r1Lo, w1H, hb1, z1);
  k_head2<<<128,256,0,stream>>>(z1, hw2, hb2, hw3, hb3, out);
}

// Round 10
// 4792.006 us; speedup vs baseline: 1.3513x; 1.1414x over previous
//
#include <hip/hip_runtime.h>
#include <math.h>

// ---------------------------------------------------------------------------
// CLSADecoder: 2-layer RowSharedConvLSTM + inter-attn + causal self-attn + head
// B=128, T=64, D=2048 (ROWS=8, CH=32, COLS=8), S=128.
// R9: inter-attention MFMA-ized (k_attn): per b, S = enc_b @ st^T (K=2048,
// 2-pass hi/lo), column softmax, ctx = a^T @ enc_b via pre-transposed encT.
// Encoder read 2x per call (256 MB) instead of 64x (4.3 GB). Replaces
// k_inter_b. Cells unchanged from R8 (conflict-free packed-u32 weights).
// ---------------------------------------------------------------------------

typedef _Float16 f16;
typedef _Float16 f16x8 __attribute__((ext_vector_type(8)));
typedef _Float16 f16x4 __attribute__((ext_vector_type(4)));
typedef float  f32x16 __attribute__((ext_vector_type(16)));
typedef float  f32x4v __attribute__((ext_vector_type(4)));
typedef unsigned short u16x8 __attribute__((ext_vector_type(8)));
typedef unsigned short u16x4 __attribute__((ext_vector_type(4)));

#define BD 262144   // 128*2048  (one [B][D] plane)

__device__ __forceinline__ unsigned short f2bf(float x){
  unsigned int u = __builtin_bit_cast(unsigned int, x);
  u += 0x7fffu + ((u >> 16) & 1u);
  return (unsigned short)(u >> 16);
}
__device__ __forceinline__ float bf2f(unsigned short h){
  unsigned int u = ((unsigned int)h) << 16;
  return __builtin_bit_cast(float, u);
}
__device__ __forceinline__ float sigmoidf_(float x){
  return 1.0f / (1.0f + __expf(-x));
}
__device__ __forceinline__ void g2l16(const void* g, void* l){
  __builtin_amdgcn_global_load_lds(
      (const __attribute__((address_space(1))) unsigned int*)g,
      (__attribute__((address_space(3))) unsigned int*)l,
      16, 0, 0);
}

// ---------------------------------------------------------------------------
// transpose f32 weight [K][N] -> f16 plane [N][K]
// ---------------------------------------------------------------------------
__global__ __launch_bounds__(256) void k_transpose_f16(
    const float* __restrict__ src, f16* __restrict__ dhi,
    const int K, const int N)
{
  __shared__ float tile[32][33];
  const int n0 = blockIdx.x * 32, k0 = blockIdx.y * 32;
  const int tx = threadIdx.x & 31, ty = threadIdx.x >> 5;
  #pragma unroll
  for (int ii = 0; ii < 4; ++ii){
    const int k = k0 + ty + ii*8, n = n0 + tx;
    float v = (n < N) ? src[(size_t)k * N + n] : 0.0f;
    tile[ty + ii*8][tx] = v;
  }
  __syncthreads();
  #pragma unroll
  for (int ii = 0; ii < 4; ++ii){
    const int n = n0 + ty + ii*8, k = k0 + tx;
    dhi[(size_t)n * K + k] = (f16)tile[tx][ty + ii*8];
  }
}

// enc f32 -> encF (f16, [b][s][d]) and encT (f16, [b][d][s])
__global__ __launch_bounds__(256) void k_enc_prep(
    const float* __restrict__ enc,
    f16* __restrict__ encF, f16* __restrict__ encT)
{
  __shared__ float tile[32][33];
  const int dt = blockIdx.x;   // 0..63
  const int st = blockIdx.y;   // 0..3
  const int b  = blockIdx.z;   // 0..127
  const int tx = threadIdx.x & 31, ty = threadIdx.x >> 5;
  const int d0 = dt*32, s0 = st*32;
  #pragma unroll
  for (int ii = 0; ii < 4; ++ii){
    const int s = s0 + ty + ii*8, d = d0 + tx;
    const float v = enc[((size_t)b*128 + s)*2048 + d];
    tile[ty + ii*8][tx] = v;
    encF[((size_t)b*128 + s)*2048 + d] = (f16)v;
  }
  __syncthreads();
  #pragma unroll
  for (int ii = 0; ii < 4; ++ii){
    const int d = d0 + ty + ii*8, s = s0 + tx;
    encT[((size_t)b*2048 + d)*128 + s] = (f16)tile[tx][ty + ii*8];
  }
}

// pack cell1 conv weights into u32 pairs: wp32[(icg*3 + w)*128 + gc]
__global__ void k_pack_cellw(const float* __restrict__ chw,
                             const float* __restrict__ cxw,
                             unsigned int* __restrict__ wp32)
{
  const int i = blockIdx.x * 256 + threadIdx.x;   // i = gc*32 + icg
  if (i < 128 * 32){
    const int gc = i >> 5, icg = i & 31;
    unsigned short tap[6];
    #pragma unroll
    for (int k = 0; k < 3; ++k){
      tap[k]   = f2bf(chw[i*3 + k]);
      tap[3+k] = f2bf(cxw[i*3 + k]);
    }
    #pragma unroll
    for (int w = 0; w < 3; ++w)
      wp32[(icg*3 + w)*128 + gc] =
          (unsigned int)tap[2*w] | ((unsigned int)tap[2*w+1] << 16);
  }
}

// ---------------------------------------------------------------------------
// Layer-0 ConvLSTM for ALL 64 steps. Block=(b,row).
// ---------------------------------------------------------------------------
__global__ __launch_bounds__(256) void k_cell0(
    const float* __restrict__ x_flat,
    const float* __restrict__ h0, const float* __restrict__ c0,
    const float* __restrict__ cxw, const float* __restrict__ cxb,
    const float* __restrict__ chw, const float* __restrict__ chb,
    f16* __restrict__ hrawHi, f16* __restrict__ hrawLo)     // [T][B][2048]
{
  const int b = blockIdx.x >> 3, row = blockIdx.x & 7;
  const int tid = threadIdx.x;
  __shared__ float h_lds[264];
  __shared__ float x_lds[8];
  __shared__ float P[128][2][9];
  const int gc = tid >> 1, ih = tid & 1;
  float wh[16][3];
  #pragma unroll
  for (int icl = 0; icl < 16; ++icl)
    #pragma unroll
    for (int k = 0; k < 3; ++k)
      wh[icl][k] = chw[(gc*32 + ih*16 + icl)*3 + k];
  const float wx0 = cxw[gc*3+0], wx1 = cxw[gc*3+1], wx2 = cxw[gc*3+2];
  const float bsum = cxb[gc] + chb[gc];
  const int ic = tid >> 3, col = tid & 7;
  const size_t dg = (size_t)b*2048 + row*256 + tid;
  const int wofs = tid + ((tid >> 7) << 2);
  const int hbase = ih * 132;
  float c_reg = c0[dg];
  h_lds[wofs] = h0[dg];
  float xnext = (tid < 8) ? x_flat[((size_t)b*64 + 0)*64 + row*8 + tid] : 0.f;
  __syncthreads();
  for (int t = 0; t < 64; ++t){
    if (tid < 8) x_lds[tid] = xnext;
    __syncthreads();
    if (t < 63 && tid < 8)
      xnext = x_flat[((size_t)b*64 + t + 1)*64 + row*8 + tid];
    float g8[8];
    #pragma unroll
    for (int c2 = 0; c2 < 8; ++c2) g8[c2] = 0.f;
    #pragma unroll
    for (int icl = 0; icl < 16; ++icl){
      const float* hb = &h_lds[icl*8 + hbase];
      f32x4v hv0 = *reinterpret_cast<const f32x4v*>(hb);
      f32x4v hv1 = *reinterpret_cast<const f32x4v*>(hb + 4);
      const float hv[8] = {hv0[0],hv0[1],hv0[2],hv0[3],hv1[0],hv1[1],hv1[2],hv1[3]};
      #pragma unroll
      for (int c2 = 0; c2 < 8; ++c2){
        float s = hv[c2] * wh[icl][1];
        if (c2 > 0) s += hv[c2-1] * wh[icl][0];
        if (c2 < 7) s += hv[c2+1] * wh[icl][2];
        g8[c2] += s;
      }
    }
    if (ih == 0){
      #pragma unroll
      for (int c2 = 0; c2 < 8; ++c2){
        float s = x_lds[c2] * wx1 + bsum;
        if (c2 > 0) s += x_lds[c2-1] * wx0;
        if (c2 < 7) s += x_lds[c2+1] * wx2;
        g8[c2] += s;
      }
    }
    #pragma unroll
    for (int c2 = 0; c2 < 8; ++c2) P[gc][ih][c2] = g8[c2];
    __syncthreads();
    const float ipre = P[ic   ][0][col] + P[ic   ][1][col];
    const float fpre = P[ic+32][0][col] + P[ic+32][1][col];
    const float opre = P[ic+64][0][col] + P[ic+64][1][col];
    const float gpre = P[ic+96][0][col] + P[ic+96][1][col];
    const float cn = sigmoidf_(fpre)*c_reg + sigmoidf_(ipre)*tanhf(gpre);
    c_reg = cn;
    const float hn = sigmoidf_(opre)*tanhf(cn);
    const f16 hh = (f16)hn;
    hrawHi[((size_t)t*128 + b)*2048 + row*256 + tid] = hh;
    hrawLo[((size_t)t*128 + b)*2048 + row*256 + tid] = (f16)(hn - (float)hh);
    __syncthreads();
    h_lds[wofs] = hn;
  }
}

// ---------------------------------------------------------------------------
// Layer-1 ConvLSTM for ALL 64 steps. Packed-u32 LDS weights (conflict-free),
// padded h/x LDS, padded P.
// ---------------------------------------------------------------------------
__global__ __launch_bounds__(256) void k_cell1_all(
    const f16* __restrict__ r0Hi, const f16* __restrict__ r0Lo,
    const float* __restrict__ h0s, const float* __restrict__ c0s,
    const unsigned int* __restrict__ wp32,     // [(icg*3+w)*128+gc]
    const float* __restrict__ cxb, const float* __restrict__ chb,
    f16* __restrict__ hrw1Hi, f16* __restrict__ hrw1Lo)            // [T][B][2048]
{
  const int b = blockIdx.x >> 3, row = blockIdx.x & 7;
  const int tid = threadIdx.x;
  __shared__ float x_lds[264];
  __shared__ float h_lds[264];
  __shared__ float P[128][2][9];
  __shared__ unsigned int wlds32[96*128];      // 48 KB
  const int gc = tid >> 1, ih = tid & 1;
  for (int i = tid; i < 96*128; i += 256) wlds32[i] = wp32[i];
  const size_t dg = (size_t)b*2048 + row*256 + tid;
  const int ic = tid >> 3, col = tid & 7;
  const float bi = cxb[ic]    + chb[ic];
  const float bf = cxb[ic+32] + chb[ic+32];
  const float bo = cxb[ic+64] + chb[ic+64];
  const float bg = cxb[ic+96] + chb[ic+96];
  const int wofs = tid + ((tid >> 7) << 2);
  const int hbase = ih * 132;
  float c_reg = c0s[dg];
  h_lds[wofs] = h0s[dg];
  float xnext = (float)r0Hi[dg] + (float)r0Lo[dg];
  __syncthreads();
  for (int t = 0; t < 64; ++t){
    x_lds[wofs] = xnext;
    __syncthreads();
    if (t < 63)
      xnext = (float)r0Hi[(size_t)(t+1)*BD + dg] + (float)r0Lo[(size_t)(t+1)*BD + dg];
    {
      float g8[8];
      #pragma unroll
      for (int c2 = 0; c2 < 8; ++c2) g8[c2] = 0.f;
      #pragma unroll
      for (int icl = 0; icl < 16; ++icl){
        const int icg = ih*16 + icl;
        const float* hb = &h_lds[icl*8 + hbase];
        const float* xb = &x_lds[icl*8 + hbase];
        f32x4v hv0 = *reinterpret_cast<const f32x4v*>(hb);
        f32x4v hv1 = *reinterpret_cast<const f32x4v*>(hb + 4);
        f32x4v xv0 = *reinterpret_cast<const f32x4v*>(xb);
        f32x4v xv1 = *reinterpret_cast<const f32x4v*>(xb + 4);
        const float hv[8] = {hv0[0],hv0[1],hv0[2],hv0[3],hv1[0],hv1[1],hv1[2],hv1[3]};
        const float xv[8] = {xv0[0],xv0[1],xv0[2],xv0[3],xv1[0],xv1[1],xv1[2],xv1[3]};
        const unsigned int* wq = &wlds32[icg*3*128 + gc];
        const unsigned int w0 = wq[0], w1 = wq[128], w2 = wq[256];
        const float wh0 = bf2f((unsigned short)(w0 & 0xffffu));
        const float wh1 = bf2f((unsigned short)(w0 >> 16));
        const float wh2 = bf2f((unsigned short)(w1 & 0xffffu));
        const float wx0 = bf2f((unsigned short)(w1 >> 16));
        const float wx1 = bf2f((unsigned short)(w2 & 0xffffu));
        const float wx2 = bf2f((unsigned short)(w2 >> 16));
        #pragma unroll
        for (int c2 = 0; c2 < 8; ++c2){
          float s = hv[c2]*wh1 + xv[c2]*wx1;
          if (c2 > 0) s += hv[c2-1]*wh0 + xv[c2-1]*wx0;
          if (c2 < 7) s += hv[c2+1]*wh2 + xv[c2+1]*wx2;
          g8[c2] += s;
        }
      }
      #pragma unroll
      for (int c2 = 0; c2 < 8; ++c2) P[gc][ih][c2] = g8[c2];
    }
    __syncthreads();
    {
      const float ipre = P[ic   ][0][col] + P[ic   ][1][col] + bi;
      const float fpre = P[ic+32][0][col] + P[ic+32][1][col] + bf;
      const float opre = P[ic+64][0][col] + P[ic+64][1][col] + bo;
      const float gpre = P[ic+96][0][col] + P[ic+96][1][col] + bg;
      const float cn = sigmoidf_(fpre)*c_reg + sigmoidf_(ipre)*tanhf(gpre);
      c_reg = cn;
      const float hraw = sigmoidf_(opre)*tanhf(cn);
      const f16 hh = (f16)hraw;
      hrw1Hi[(size_t)t*BD + dg] = hh;
      hrw1Lo[(size_t)t*BD + dg] = (f16)(hraw - (float)hh);
      __syncthreads();
      h_lds[wofs] = hraw;
    }
  }
}

// ---------------------------------------------------------------------------
// MFMA inter-attention: block (b, t-half of 32). Phase1 S=encF@st^T (K=2048,
// 2-pass st hi/lo), phase2 column softmax, phase3 ctx = a^T @ enc via encT.
// ---------------------------------------------------------------------------
__global__ __launch_bounds__(256) void k_attn(
    const f16* __restrict__ encF,    // [128][128][2048]
    const f16* __restrict__ encT,    // [128][2048][128]
    const f16* __restrict__ stHi, const f16* __restrict__ stLo,  // [T][B][2048]
    f16* __restrict__ ctxHi, f16* __restrict__ ctxLo)            // [T][B][2048]
{
  const int b = blockIdx.x, th = blockIdx.y;
  const int tid = threadIdx.x, lane = tid & 63, wv = tid >> 6;
  __shared__ float S_lds[128][36];
  __shared__ float red[8][32];
  __shared__ float colv[32];
  __shared__ __align__(16) char aT[8192];   // [32 t][16 chunks of 8 f16], XOR swizzled
  const int kb = lane >> 5;
  // ---- phase 1: S[s][t] = sum_d encF[b][s][d] * st[t][d]
  {
    const int rA = wv*32 + (lane & 31);
    const int tcol = th*32 + (lane & 31);
    const f16* pA  = encF + ((size_t)b*128 + rA)*2048 + kb*8;
    const f16* pBH = stHi + ((size_t)tcol*128 + b)*2048 + kb*8;
    const f16* pBL = stLo + ((size_t)tcol*128 + b)*2048 + kb*8;
    f32x16 acc;
    #pragma unroll
    for (int r = 0; r < 16; ++r) acc[r] = 0.f;
    #pragma unroll 4
    for (int s = 0; s < 128; ++s){
      f16x8 av = *reinterpret_cast<const f16x8*>(pA  + s*16);
      f16x8 bh = *reinterpret_cast<const f16x8*>(pBH + s*16);
      f16x8 bl = *reinterpret_cast<const f16x8*>(pBL + s*16);
      acc = __builtin_amdgcn_mfma_f32_32x32x16_f16(av, bh, acc, 0, 0, 0);
      acc = __builtin_amdgcn_mfma_f32_32x32x16_f16(av, bl, acc, 0, 0, 0);
    }
    #pragma unroll
    for (int r = 0; r < 16; ++r){
      const int rr = 4*kb + (r & 3) + 8*(r >> 2);
      S_lds[wv*32 + rr][lane & 31] = acc[r];
    }
  }
  __syncthreads();
  // ---- phase 2: softmax over s (rows) per t column
  {
    const int c = tid & 31, g = tid >> 5;
    float ev[16];
    float m = -INFINITY;
    #pragma unroll
    for (int i = 0; i < 16; ++i){ ev[i] = S_lds[g*16 + i][c]; m = fmaxf(m, ev[i]); }
    red[g][c] = m;
    __syncthreads();
    if (tid < 32){
      float M = red[0][tid];
      #pragma unroll
      for (int j = 1; j < 8; ++j) M = fmaxf(M, red[j][tid]);
      colv[tid] = M;
    }
    __syncthreads();
    const float M = colv[c];
    float sum = 0.f;
    #pragma unroll
    for (int i = 0; i < 16; ++i){ ev[i] = __expf(ev[i] - M); sum += ev[i]; }
    __syncthreads();
    red[g][c] = sum;
    __syncthreads();
    if (tid < 32){
      float L = red[0][tid];
      #pragma unroll
      for (int j = 1; j < 8; ++j) L += red[j][tid];
      colv[tid] = 1.f / L;
    }
    __syncthreads();
    const float inv = colv[c];
    f16x8 w0, w1;
    #pragma unroll
    for (int j = 0; j < 8; ++j){
      w0[j] = (f16)(ev[j] * inv);
      w1[j] = (f16)(ev[8 + j] * inv);
    }
    const int sw = (c & 15) << 4;
    *reinterpret_cast<f16x8*>(aT + c*256 + (((g*2    )*16) ^ sw)) = w0;
    *reinterpret_cast<f16x8*>(aT + c*256 + (((g*2 + 1)*16) ^ sw)) = w1;
  }
  __syncthreads();
  // ---- phase 3: ctx[t][d] = sum_s a[s][t] * enc[s][d]  (K=128)
  {
    const int arow = lane & 31;
    const int asw = (arow & 15) << 4;
    f16x8 afr[8];
    #pragma unroll
    for (int ks = 0; ks < 8; ++ks){
      const int chunk = 2*ks + kb;
      afr[ks] = *reinterpret_cast<const f16x8*>(aT + arow*256 + ((chunk*16) ^ asw));
    }
    for (int nt = wv; nt < 64; nt += 4){
      const int d = nt*32 + (lane & 31);
      const f16* pB = encT + ((size_t)b*2048 + d)*128 + kb*8;
      f32x16 acc;
      #pragma unroll
      for (int r = 0; r < 16; ++r) acc[r] = 0.f;
      #pragma unroll
      for (int ks = 0; ks < 8; ++ks){
        f16x8 bv = *reinterpret_cast<const f16x8*>(pB + ks*16);
        acc = __builtin_amdgcn_mfma_f32_32x32x16_f16(afr[ks], bv, acc, 0, 0, 0);
      }
      #pragma unroll
      for (int r = 0; r < 16; ++r){
        const int rr = 4*kb + (r & 3) + 8*(r >> 2);
        const size_t o = ((size_t)(th*32 + rr)*128 + b)*2048 + d;
        const float v = acc[r];
        const f16 hh = (f16)v;
        ctxHi[o] = hh;
        ctxLo[o] = (f16)(v - (float)hh);
      }
    }
  }
}

// ---------------------------------------------------------------------------
// Batched full-K ia GEMM (all t): p[t] = tanh([A0|A1]@W + bias), f16 hi/lo.
// ---------------------------------------------------------------------------
__global__ __launch_bounds__(256, 2) void k_gemm_full(
    const f16* __restrict__ a0Hi, const f16* __restrict__ a0Lo,
    const f16* __restrict__ a1Hi, const f16* __restrict__ a1Lo,
    const f16* __restrict__ wHp, const float* __restrict__ bias,
    f16* __restrict__ outHi, f16* __restrict__ outLo)
{
  const int nt = blockIdx.x, t = blockIdx.y;
  const size_t tb = (size_t)t * BD;
  const int tid = threadIdx.x;
  const int lane = tid & 63, wv = tid >> 6;
  __shared__ __align__(16) char lds[81920];
  const f16* wH = wHp + (size_t)(nt*64)*4096;

  auto stage = [&](int buf, int ki){
    char* lb = lds + buf*40960;
    const f16* aH = ((ki < 32) ? a0Hi : a1Hi) + tb;
    const f16* aL = ((ki < 32) ? a0Lo : a1Lo) + tb;
    const int ke = (ki & 31) * 64;
    #pragma unroll
    for (int i = 0; i < 4; ++i){
      const int c = i*256 + tid, row = c >> 3;
      const int srcb = ((c & 7)*16) ^ ((row & 7) << 4);
      g2l16((const char*)(aH + (size_t)row*2048 + ke) + srcb, lb + c*16);
      g2l16((const char*)(aL + (size_t)row*2048 + ke) + srcb, lb + 16384 + c*16);
    }
    #pragma unroll
    for (int i = 0; i < 2; ++i){
      const int c = i*256 + tid, row = c >> 3;
      const int srcb = ((c & 7)*16) ^ ((row & 7) << 4);
      g2l16((const char*)(wH + (size_t)row*4096 + ki*64) + srcb, lb + 32768 + c*16);
    }
  };

  f32x16 acc0, acc1;
  #pragma unroll
  for (int r = 0; r < 16; ++r){ acc0[r] = 0.f; acc1[r] = 0.f; }
  const int rA = wv*32 + (lane & 31);
  const int kb = lane >> 5;
  const int rB0 = lane & 31;
  const int aswz = (rA & 7) << 4;
  const int bswz = (rB0 & 7) << 4;

  stage(0, 0);
  __syncthreads();
  for (int ki = 0; ki < 64; ++ki){
    const int buf = ki & 1;
    if (ki < 63) stage(buf ^ 1, ki + 1);
    const char* lb = lds + buf*40960;
    #pragma unroll
    for (int s = 0; s < 4; ++s){
      const int cb = s*32 + kb*16;
      f16x8 ah  = *reinterpret_cast<const f16x8*>(lb + rA*128 + (cb ^ aswz));
      f16x8 al  = *reinterpret_cast<const f16x8*>(lb + 16384 + rA*128 + (cb ^ aswz));
      f16x8 b0h = *reinterpret_cast<const f16x8*>(lb + 32768 + rB0*128 + (cb ^ bswz));
      f16x8 b1h = *reinterpret_cast<const f16x8*>(lb + 32768 + 4096 + rB0*128 + (cb ^ bswz));
      acc0 = __builtin_amdgcn_mfma_f32_32x32x16_f16(ah, b0h, acc0, 0, 0, 0);
      acc1 = __builtin_amdgcn_mfma_f32_32x32x16_f16(ah, b1h, acc1, 0, 0, 0);
      acc0 = __builtin_amdgcn_mfma_f32_32x32x16_f16(al, b0h, acc0, 0, 0, 0);
      acc1 = __builtin_amdgcn_mfma_f32_32x32x16_f16(al, b1h, acc1, 0, 0, 0);
    }
    __syncthreads();
  }

  const int col0 = nt*64 + (lane & 31);
  const float b0 = bias[col0], b1 = bias[col0 + 32];
  const int rowBase = wv*32 + 4*kb;
  #pragma unroll
  for (int r = 0; r < 16; ++r){
    const int rr = rowBase + (r & 3) + 8*(r >> 2);
    const size_t o = tb + (size_t)rr*2048 + col0;
    const float p = tanhf(acc0[r] + b0);
    const float q = tanhf(acc1[r] + b1);
    const f16 ph = (f16)p, qh = (f16)q;
    outHi[o]      = ph;  outLo[o]      = (f16)(p - (float)ph);
    outHi[o + 32] = qh;  outLo[o + 32] = (f16)(q - (float)qh);
  }
}

// ---------------------------------------------------------------------------
// Batched sa GEMM (all t): A = p hi/lo, W = [Wlow^T|Wup^T] ([4096][2048]).
// nt<32 -> Y (f32, raw); nt>=32 -> G (f16). Grid (64 nt, 64 t), K=2048.
// ---------------------------------------------------------------------------
__global__ __launch_bounds__(256, 2) void k_gemm_full2(
    const f16* __restrict__ aHi, const f16* __restrict__ aLo,   // [T][B][2048]
    const f16* __restrict__ wSp,                                // [4096][2048]
    float* __restrict__ Y, f16* __restrict__ G)                 // [T][B][2048]
{
  const int nt = blockIdx.x, t = blockIdx.y;
  const size_t tb = (size_t)t * BD;
  const int tid = threadIdx.x;
  const int lane = tid & 63, wv = tid >> 6;
  __shared__ __align__(16) char lds[81920];
  const f16* wH = wSp + (size_t)(nt*64)*2048;
  const f16* aH = aHi + tb;
  const f16* aL = aLo + tb;

  auto stage = [&](int buf, int ki){
    char* lb = lds + buf*40960;
    const int ke = ki*64;
    #pragma unroll
    for (int i = 0; i < 4; ++i){
      const int c = i*256 + tid, row = c >> 3;
      const int srcb = ((c & 7)*16) ^ ((row & 7) << 4);
      g2l16((const char*)(aH + (size_t)row*2048 + ke) + srcb, lb + c*16);
      g2l16((const char*)(aL + (size_t)row*2048 + ke) + srcb, lb + 16384 + c*16);
    }
    #pragma unroll
    for (int i = 0; i < 2; ++i){
      const int c = i*256 + tid, row = c >> 3;
      const int srcb = ((c & 7)*16) ^ ((row & 7) << 4);
      g2l16((const char*)(wH + (size_t)row*2048 + ke) + srcb, lb + 32768 + c*16);
    }
  };

  f32x16 acc0, acc1;
  #pragma unroll
  for (int r = 0; r < 16; ++r){ acc0[r] = 0.f; acc1[r] = 0.f; }
  const int rA = wv*32 + (lane & 31);
  const int kb = lane >> 5;
  const int rB0 = lane & 31;
  const int aswz = (rA & 7) << 4;
  const int bswz = (rB0 & 7) << 4;

  stage(0, 0);
  __syncthreads();
  for (int ki = 0; ki < 32; ++ki){
    const int buf = ki & 1;
    if (ki < 31) stage(buf ^ 1, ki + 1);
    const char* lb = lds + buf*40960;
    #pragma unroll
    for (int s = 0; s < 4; ++s){
      const int cb = s*32 + kb*16;
      f16x8 ah  = *reinterpret_cast<const f16x8*>(lb + rA*128 + (cb ^ aswz));
      f16x8 al  = *reinterpret_cast<const f16x8*>(lb + 16384 + rA*128 + (cb ^ aswz));
      f16x8 b0h = *reinterpret_cast<const f16x8*>(lb + 32768 + rB0*128 + (cb ^ bswz));
      f16x8 b1h = *reinterpret_cast<const f16x8*>(lb + 32768 + 4096 + rB0*128 + (cb ^ bswz));
      acc0 = __builtin_amdgcn_mfma_f32_32x32x16_f16(ah, b0h, acc0, 0, 0, 0);
      acc1 = __builtin_amdgcn_mfma_f32_32x32x16_f16(ah, b1h, acc1, 0, 0, 0);
      acc0 = __builtin_amdgcn_mfma_f32_32x32x16_f16(al, b0h, acc0, 0, 0, 0);
      acc1 = __builtin_amdgcn_mfma_f32_32x32x16_f16(al, b1h, acc1, 0, 0, 0);
    }
    __syncthreads();
  }

  const int col0 = nt*64 + (lane & 31);
  const int rowBase = wv*32 + 4*kb;
  if (nt < 32){
    float* yp = Y + tb + col0;
    #pragma unroll
    for (int r = 0; r < 16; ++r){
      const int rr = rowBase + (r & 3) + 8*(r >> 2);
      yp[(size_t)rr*2048]      = acc0[r];
      yp[(size_t)rr*2048 + 32] = acc1[r];
    }
  } else {
    f16* gp = G + tb + (col0 - 2048);
    #pragma unroll
    for (int r = 0; r < 16; ++r){
      const int rr = rowBase + (r & 3) + 8*(r >> 2);
      gp[(size_t)rr*2048]      = (f16)acc0[r];
      gp[(size_t)rr*2048 + 32] = (f16)acc1[r];
    }
  }
}

// ---------------------------------------------------------------------------
// Self-attention refine chain (persistent over t). Block per b, 512 threads.
// ---------------------------------------------------------------------------
__global__ __launch_bounds__(512) void k_selfchain(
    const f16* __restrict__ pHi, const f16* __restrict__ pLo,   // [T][B][2048]
    const float* __restrict__ Y, const f16* __restrict__ G,     // [T][B][2048]
    const float* __restrict__ bias,
    f16* __restrict__ rHi, f16* __restrict__ rLo)               // [T][B][2048]
{
  const int b = blockIdx.x;
  const int tid = threadIdx.x, lane = tid & 63, wv = tid >> 6;   // 8 waves
  __shared__ float sc[64];
  __shared__ float a_lds[64];
  const int d0 = tid * 4;
  f32x4v bb = *reinterpret_cast<const f32x4v*>(bias + d0);
  for (int t = 0; t < 64; ++t){
    const size_t pb = ((size_t)t*128 + b)*2048;
    if (t > 0){
      float hreg[32];
      #pragma unroll
      for (int jj = 0; jj < 4; ++jj){
        const int d = (jj*64 + lane)*8;
        f16x8 h8 = *reinterpret_cast<const f16x8*>(pHi + pb + d);
        f16x8 l8 = *reinterpret_cast<const f16x8*>(pLo + pb + d);
        #pragma unroll
        for (int j = 0; j < 8; ++j) hreg[jj*8+j] = (float)h8[j] + (float)l8[j];
      }
      for (int i = wv; i < t; i += 8){
        const f16* rh = rHi + ((size_t)i*128 + b)*2048;
        const f16* rl = rLo + ((size_t)i*128 + b)*2048;
        float dot = 0.f;
        #pragma unroll
        for (int jj = 0; jj < 4; ++jj){
          const int d = (jj*64 + lane)*8;
          f16x8 h8 = *reinterpret_cast<const f16x8*>(rh + d);
          f16x8 l8 = *reinterpret_cast<const f16x8*>(rl + d);
          #pragma unroll
          for (int j = 0; j < 8; ++j)
            dot += ((float)h8[j] + (float)l8[j]) * hreg[jj*8+j];
        }
        #pragma unroll
        for (int off = 1; off < 64; off <<= 1) dot += __shfl_xor(dot, off);
        if (lane == 0) sc[i] = dot;
      }
      __syncthreads();
      if (tid < 64){
        const float s = (tid < t) ? sc[tid] : -INFINITY;
        float mm = s;
        #pragma unroll
        for (int off = 1; off < 64; off <<= 1) mm = fmaxf(mm, __shfl_xor(mm, off));
        const float e = (tid < t) ? __expf(s - mm) : 0.f;
        float sum = e;
        #pragma unroll
        for (int off = 1; off < 64; off <<= 1) sum += __shfl_xor(sum, off);
        a_lds[tid] = e / sum;
      }
      __syncthreads();
    }
    float y[4];
    {
      f32x4v yv = *reinterpret_cast<const f32x4v*>(Y + (size_t)t*BD + (size_t)b*2048 + d0);
      #pragma unroll
      for (int j = 0; j < 4; ++j) y[j] = yv[j] + bb[j];
    }
    if (t > 0){
      for (int i = 0; i < t; ++i){
        const float a = a_lds[i];
        f16x4 g4 = *reinterpret_cast<const f16x4*>(G + ((size_t)i*128 + b)*2048 + d0);
        #pragma unroll
        for (int j = 0; j < 4; ++j) y[j] += a * (float)g4[j];
      }
    }
    f16x4 hh, ll;
    #pragma unroll
    for (int j = 0; j < 4; ++j){
      const float v = tanhf(y[j]);
      hh[j] = (f16)v;
      ll[j] = (f16)(v - (float)hh[j]);
    }
    *reinterpret_cast<f16x4*>(rHi + pb + d0) = hh;
    *reinterpret_cast<f16x4*>(rLo + pb + d0) = ll;
    __syncthreads();
  }
}

// ---------------------------------------------------------------------------
// Head stage 1: z1 = relu(r1(8192x2048) @ hw1 + hb1), f16 2-pass MFMA
// ---------------------------------------------------------------------------
__global__ __launch_bounds__(256) void k_headgemm(
    const f16* __restrict__ aHi, const f16* __restrict__ aLo,
    const f16* __restrict__ w1H,   // [224][2048]
    const float* __restrict__ hb1,
    float* __restrict__ z1)        // [8192][224]
{
  const int mb = blockIdx.x;
  const int nt = blockIdx.y;
  const int lane = threadIdx.x & 63, wv = threadIdx.x >> 6;
  const int rowA = mb*128 + wv*32 + (lane & 31);
  const int kb = lane >> 5;
  const int n = nt*32 + (lane & 31);
  const f16* pAH = aHi + (size_t)rowA*2048 + kb*8;
  const f16* pAL = aLo + (size_t)rowA*2048 + kb*8;
  const f16* pBH = w1H + (size_t)n*2048 + kb*8;
  f32x16 acc;
  #pragma unroll
  for (int r = 0; r < 16; ++r) acc[r] = 0.f;
  #pragma unroll 4
  for (int s = 0; s < 128; ++s){
    f16x8 ah = *reinterpret_cast<const f16x8*>(pAH + s*16);
    f16x8 al = *reinterpret_cast<const f16x8*>(pAL + s*16);
    f16x8 bh = *reinterpret_cast<const f16x8*>(pBH + s*16);
    acc = __builtin_amdgcn_mfma_f32_32x32x16_f16(ah, bh, acc, 0, 0, 0);
    acc = __builtin_amdgcn_mfma_f32_32x32x16_f16(al, bh, acc, 0, 0, 0);
  }
  const float bias = (n < 200) ? hb1[n] : 0.f;
  const int rowBase = mb*128 + wv*32 + 4*kb;
  #pragma unroll
  for (int r = 0; r < 16; ++r){
    const int rr = rowBase + (r & 3) + 8*(r >> 2);
    z1[(size_t)rr*224 + n] = fmaxf(acc[r] + bias, 0.f);
  }
}

// Head stage 2
__global__ __launch_bounds__(256) void k_head2(
    const float* __restrict__ z1,
    const float* __restrict__ hw2, const float* __restrict__ hb2,
    const float* __restrict__ hw3, const float* __restrict__ hb3,
    float* __restrict__ out)
{
  const int r0 = blockIdx.x * 64;
  const int tid = threadIdx.x;
  __shared__ float zl[64][200];
  __shared__ float z2[64][50];
  for (int i = tid; i < 64*200; i += 256){
    const int r = i / 200, n = i % 200;
    zl[r][n] = z1[(size_t)(r0 + r)*224 + n];
  }
  __syncthreads();
  for (int i = tid; i < 64*50; i += 256){
    const int r = i / 50, n = i % 50;
    float s = hb2[n];
    for (int k = 0; k < 200; ++k) s += zl[r][k] * hw2[k*50 + n];
    z2[r][n] = fmaxf(s, 0.f);
  }
  __syncthreads();
  for (int i = tid; i < 128; i += 256){
    const int r = i >> 1, c = i & 1;
    float s = hb3[c];
    for (int k = 0; k < 50; ++k) s += z2[r][k] * hw3[k*2 + c];
    const int rg = r0 + r;
    const int tt = rg >> 7, b = rg & 127;
    out[(size_t)b*128 + tt*2 + c] = s;
  }
}

// ---------------------------------------------------------------------------
extern "C" void kernel_launch(void* const* d_in, const int* in_sizes, int n_in,
                              void* d_out, int out_size, void* d_ws, size_t ws_size,
                              hipStream_t stream)
{
  (void)in_sizes; (void)n_in; (void)out_size; (void)ws_size;
  const float* x_flat = (const float*)d_in[0];
  const float* enc    = (const float*)d_in[1];
  const float* h0     = (const float*)d_in[2];
  const float* c0     = (const float*)d_in[3];
  const float* cx_w0  = (const float*)d_in[4];
  const float* cx_b0  = (const float*)d_in[5];
  const float* ch_w0  = (const float*)d_in[6];
  const float* ch_b0  = (const float*)d_in[7];
  const float* cx_w1  = (const float*)d_in[8];
  const float* cx_b1  = (const float*)d_in[9];
  const float* ch_w1  = (const float*)d_in[10];
  const float* ch_b1  = (const float*)d_in[11];
  const float* ia_w0  = (const float*)d_in[12];
  const float* ia_b0  = (const float*)d_in[13];
  const float* sa_w0  = (const float*)d_in[14];
  const float* sa_b0  = (const float*)d_in[15];
  const float* ia_w1  = (const float*)d_in[16];
  const float* ia_b1  = (const float*)d_in[17];
  const float* sa_w1  = (const float*)d_in[18];
  const float* sa_b1  = (const float*)d_in[19];
  const float* hw1    = (const float*)d_in[20];
  const float* hb1    = (const float*)d_in[21];
  const float* hw2    = (const float*)d_in[22];
  const float* hb2    = (const float*)d_in[23];
  const float* hw3    = (const float*)d_in[24];
  const float* hb3    = (const float*)d_in[25];
  float* out = (float*)d_out;

  char* ws = (char*)d_ws;
  size_t off = 0;
  auto alloc = [&](size_t bytes) -> char* {
    char* p = ws + off;
    off += (bytes + 255) & ~(size_t)255;
    return p;
  };
  const size_t WPLANE = (size_t)2048*4096*2;   // 16 MiB
  const size_t TPLANE = (size_t)64*BD*2;       // 32 MiB, [T][B][D] f16
  f16* wIa0 = (f16*)alloc(WPLANE);
  f16* wSa0 = (f16*)alloc(WPLANE);   // [4096][2048]: Wlow^T rows 0..2047, Wup^T rows 2048..
  f16* wIa1 = (f16*)alloc(WPLANE);
  f16* wSa1 = (f16*)alloc(WPLANE);
  f16* w1H  = (f16*)alloc((size_t)224*2048*2);
  f16* encF = (f16*)alloc((size_t)128*128*2048*2);   // 64 MiB
  f16* encT = (f16*)alloc((size_t)128*2048*128*2);   // 64 MiB
  f16* S1 = (f16*)alloc(TPLANE);
  f16* S2 = (f16*)alloc(TPLANE);
  f16* S3 = (f16*)alloc(TPLANE);
  f16* S4 = (f16*)alloc(TPLANE);
  f16* S5 = (f16*)alloc(TPLANE);
  f16* S6 = (f16*)alloc(TPLANE);
  f16* S7 = (f16*)alloc(TPLANE);
  f16* S8 = (f16*)alloc(TPLANE);
  unsigned int* wpack1 = (unsigned int*)alloc((size_t)96*128*4);
  // total ws ~= 449 MiB. Alias names (lifetimes verified disjoint):
  f16*  hr0AHi = S1;  f16* hr0ALo = S2;
  f16*  ctx0Hi = S3;  f16* ctx0Lo = S4;
  f16*  p0Hi   = S5;  f16* p0Lo   = S6;
  float* Y0 = (float*)S1;                    // 64 MiB over S1+S2 (contiguous)
  f16*  G0  = S3;
  f16*  r0Hi = S7;    f16* r0Lo   = S8;
  f16*  hrw1Hi = S5;  f16* hrw1Lo = S6;
  f16*  ctx1Hi = S1;  f16* ctx1Lo = S2;
  f16*  p1Hi = S7;    f16* p1Lo   = S8;
  float* Y1 = (float*)S1;                    // 64 MiB over S1+S2
  f16*  G1  = S4;
  f16*  r1Hi = S5;    f16* r1Lo   = S3;
  float* z1 = (float*)wSa0;                  // head scratch (wSa0 dead by then)

  // ---- prologue -----------------------------------------------------------
  k_transpose_f16<<<dim3(64,128),256,0,stream>>>(ia_w0, wIa0, 4096, 2048);
  k_transpose_f16<<<dim3(64,128),256,0,stream>>>(ia_w1, wIa1, 4096, 2048);
  k_transpose_f16<<<dim3(64,64),256,0,stream>>>(sa_w0, wSa0, 2048, 2048);
  k_transpose_f16<<<dim3(64,64),256,0,stream>>>(sa_w0 + (size_t)2048*2048,
                                                wSa0 + (size_t)2048*2048, 2048, 2048);
  k_transpose_f16<<<dim3(64,64),256,0,stream>>>(sa_w1, wSa1, 2048, 2048);
  k_transpose_f16<<<dim3(64,64),256,0,stream>>>(sa_w1 + (size_t)2048*2048,
                                                wSa1 + (size_t)2048*2048, 2048, 2048);
  k_transpose_f16<<<dim3(7,64),256,0,stream>>>(hw1, w1H, 2048, 200);
  k_enc_prep<<<dim3(64,4,128),256,0,stream>>>(enc, encF, encT);
  k_pack_cellw<<<16,256,0,stream>>>(ch_w1, cx_w1, wpack1);

  // ---- layer 0 (fully batched + one persistent chain) ---------------------
  k_cell0<<<1024,256,0,stream>>>(x_flat, h0, c0, cx_w0, cx_b0, ch_w0, ch_b0,
                                 hr0AHi, hr0ALo);
  k_attn<<<dim3(128,2),256,0,stream>>>(encF, encT, hr0AHi, hr0ALo, ctx0Hi, ctx0Lo);
  k_gemm_full<<<dim3(32,64),256,0,stream>>>(hr0AHi, hr0ALo, ctx0Hi, ctx0Lo,
                                            wIa0, ia_b0, p0Hi, p0Lo);
  k_gemm_full2<<<dim3(64,64),256,0,stream>>>(p0Hi, p0Lo, wSa0, Y0, G0);
  k_selfchain<<<128,512,0,stream>>>(p0Hi, p0Lo, Y0, G0, sa_b0, r0Hi, r0Lo);

  // ---- layer 1 (persistent cell + fully batched + one persistent chain) ---
  k_cell1_all<<<1024,256,0,stream>>>(r0Hi, r0Lo,
                                     h0 + (size_t)128*2048, c0 + (size_t)128*2048,
                                     wpack1, cx_b1, ch_b1, hrw1Hi, hrw1Lo);
  k_attn<<<dim3(128,2),256,0,stream>>>(encF, encT, hrw1Hi, hrw1Lo, ctx1Hi, ctx1Lo);
  k_gemm_full<<<dim3(32,64),256,0,stream>>>(hrw1Hi, hrw1Lo, ctx1Hi, ctx1Lo,
                                            wIa1, ia_b1, p1Hi, p1Lo);
  k_gemm_full2<<<dim3(64,64),256,0,stream>>>(p1Hi, p1Lo, wSa1, Y1, G1);
  k_selfchain<<<128,512,0,stream>>>(p1Hi, p1Lo, Y1, G1, sa_b1, r1Hi, r1Lo);

  // ---- head (batched over all t,b) ----------------------------------------
  k_headgemm<<<dim3(64,7),256,0,stream>>>(r1Hi, r1Lo, w1H, hb1, z1);
  k_head2<<<128,256,0,stream>>>(z1, hw2, hb2, hw3, hb3, out);
}

// Round 11
// 4118.797 us; speedup vs baseline: 1.5721x; 1.1634x over previous
//
#include <hip/hip_runtime.h>
#include <math.h>

// ---------------------------------------------------------------------------
// CLSADecoder: 2-layer RowSharedConvLSTM + inter-attn + causal self-attn + head
// B=128, T=64, D=2048 (ROWS=8, CH=32, COLS=8), S=128.
// R10: precision-dividend round. Error analysis: W-f16 rounding dominates all
// GEMM outputs (~1e-4); the A-side lo-compensation pass adds only ~3e-5. So
// all GEMMs (gemm_full, gemm_full2, headgemm, attn) go single-pass A (halved
// MFMA + staging), and the now-unconsumed lo planes (hrawLo, hrw1Lo, ctxLo)
// are no longer computed/written (-96 MB HBM writes). Lo planes kept where
// they matter: selfchain score dots and cell1's x input.
// ---------------------------------------------------------------------------

typedef _Float16 f16;
typedef _Float16 f16x8 __attribute__((ext_vector_type(8)));
typedef _Float16 f16x4 __attribute__((ext_vector_type(4)));
typedef float  f32x16 __attribute__((ext_vector_type(16)));
typedef float  f32x4v __attribute__((ext_vector_type(4)));
typedef unsigned short u16x8 __attribute__((ext_vector_type(8)));
typedef unsigned short u16x4 __attribute__((ext_vector_type(4)));

#define BD 262144   // 128*2048  (one [B][D] plane)

__device__ __forceinline__ unsigned short f2bf(float x){
  unsigned int u = __builtin_bit_cast(unsigned int, x);
  u += 0x7fffu + ((u >> 16) & 1u);
  return (unsigned short)(u >> 16);
}
__device__ __forceinline__ float bf2f(unsigned short h){
  unsigned int u = ((unsigned int)h) << 16;
  return __builtin_bit_cast(float, u);
}
__device__ __forceinline__ float sigmoidf_(float x){
  return 1.0f / (1.0f + __expf(-x));
}
__device__ __forceinline__ void g2l16(const void* g, void* l){
  __builtin_amdgcn_global_load_lds(
      (const __attribute__((address_space(1))) unsigned int*)g,
      (__attribute__((address_space(3))) unsigned int*)l,
      16, 0, 0);
}

// ---------------------------------------------------------------------------
// transpose f32 weight [K][N] -> f16 plane [N][K]
// ---------------------------------------------------------------------------
__global__ __launch_bounds__(256) void k_transpose_f16(
    const float* __restrict__ src, f16* __restrict__ dhi,
    const int K, const int N)
{
  __shared__ float tile[32][33];
  const int n0 = blockIdx.x * 32, k0 = blockIdx.y * 32;
  const int tx = threadIdx.x & 31, ty = threadIdx.x >> 5;
  #pragma unroll
  for (int ii = 0; ii < 4; ++ii){
    const int k = k0 + ty + ii*8, n = n0 + tx;
    float v = (n < N) ? src[(size_t)k * N + n] : 0.0f;
    tile[ty + ii*8][tx] = v;
  }
  __syncthreads();
  #pragma unroll
  for (int ii = 0; ii < 4; ++ii){
    const int n = n0 + ty + ii*8, k = k0 + tx;
    dhi[(size_t)n * K + k] = (f16)tile[tx][ty + ii*8];
  }
}

// enc f32 -> encF (f16, [b][s][d]) and encT (f16, [b][d][s])
__global__ __launch_bounds__(256) void k_enc_prep(
    const float* __restrict__ enc,
    f16* __restrict__ encF, f16* __restrict__ encT)
{
  __shared__ float tile[32][33];
  const int dt = blockIdx.x;   // 0..63
  const int st = blockIdx.y;   // 0..3
  const int b  = blockIdx.z;   // 0..127
  const int tx = threadIdx.x & 31, ty = threadIdx.x >> 5;
  const int d0 = dt*32, s0 = st*32;
  #pragma unroll
  for (int ii = 0; ii < 4; ++ii){
    const int s = s0 + ty + ii*8, d = d0 + tx;
    const float v = enc[((size_t)b*128 + s)*2048 + d];
    tile[ty + ii*8][tx] = v;
    encF[((size_t)b*128 + s)*2048 + d] = (f16)v;
  }
  __syncthreads();
  #pragma unroll
  for (int ii = 0; ii < 4; ++ii){
    const int d = d0 + ty + ii*8, s = s0 + tx;
    encT[((size_t)b*2048 + d)*128 + s] = (f16)tile[tx][ty + ii*8];
  }
}

// pack cell1 conv weights into u32 pairs: wp32[(icg*3 + w)*128 + gc]
__global__ void k_pack_cellw(const float* __restrict__ chw,
                             const float* __restrict__ cxw,
                             unsigned int* __restrict__ wp32)
{
  const int i = blockIdx.x * 256 + threadIdx.x;   // i = gc*32 + icg
  if (i < 128 * 32){
    const int gc = i >> 5, icg = i & 31;
    unsigned short tap[6];
    #pragma unroll
    for (int k = 0; k < 3; ++k){
      tap[k]   = f2bf(chw[i*3 + k]);
      tap[3+k] = f2bf(cxw[i*3 + k]);
    }
    #pragma unroll
    for (int w = 0; w < 3; ++w)
      wp32[(icg*3 + w)*128 + gc] =
          (unsigned int)tap[2*w] | ((unsigned int)tap[2*w+1] << 16);
  }
}

// ---------------------------------------------------------------------------
// Layer-0 ConvLSTM for ALL 64 steps. Block=(b,row). Writes hraw hi only.
// ---------------------------------------------------------------------------
__global__ __launch_bounds__(256) void k_cell0(
    const float* __restrict__ x_flat,
    const float* __restrict__ h0, const float* __restrict__ c0,
    const float* __restrict__ cxw, const float* __restrict__ cxb,
    const float* __restrict__ chw, const float* __restrict__ chb,
    f16* __restrict__ hrawHi)     // [T][B][2048]
{
  const int b = blockIdx.x >> 3, row = blockIdx.x & 7;
  const int tid = threadIdx.x;
  __shared__ float h_lds[264];
  __shared__ float x_lds[8];
  __shared__ float P[128][2][9];
  const int gc = tid >> 1, ih = tid & 1;
  float wh[16][3];
  #pragma unroll
  for (int icl = 0; icl < 16; ++icl)
    #pragma unroll
    for (int k = 0; k < 3; ++k)
      wh[icl][k] = chw[(gc*32 + ih*16 + icl)*3 + k];
  const float wx0 = cxw[gc*3+0], wx1 = cxw[gc*3+1], wx2 = cxw[gc*3+2];
  const float bsum = cxb[gc] + chb[gc];
  const int ic = tid >> 3, col = tid & 7;
  const size_t dg = (size_t)b*2048 + row*256 + tid;
  const int wofs = tid + ((tid >> 7) << 2);
  const int hbase = ih * 132;
  float c_reg = c0[dg];
  h_lds[wofs] = h0[dg];
  float xnext = (tid < 8) ? x_flat[((size_t)b*64 + 0)*64 + row*8 + tid] : 0.f;
  __syncthreads();
  for (int t = 0; t < 64; ++t){
    if (tid < 8) x_lds[tid] = xnext;
    __syncthreads();
    if (t < 63 && tid < 8)
      xnext = x_flat[((size_t)b*64 + t + 1)*64 + row*8 + tid];
    float g8[8];
    #pragma unroll
    for (int c2 = 0; c2 < 8; ++c2) g8[c2] = 0.f;
    #pragma unroll
    for (int icl = 0; icl < 16; ++icl){
      const float* hb = &h_lds[icl*8 + hbase];
      f32x4v hv0 = *reinterpret_cast<const f32x4v*>(hb);
      f32x4v hv1 = *reinterpret_cast<const f32x4v*>(hb + 4);
      const float hv[8] = {hv0[0],hv0[1],hv0[2],hv0[3],hv1[0],hv1[1],hv1[2],hv1[3]};
      #pragma unroll
      for (int c2 = 0; c2 < 8; ++c2){
        float s = hv[c2] * wh[icl][1];
        if (c2 > 0) s += hv[c2-1] * wh[icl][0];
        if (c2 < 7) s += hv[c2+1] * wh[icl][2];
        g8[c2] += s;
      }
    }
    if (ih == 0){
      #pragma unroll
      for (int c2 = 0; c2 < 8; ++c2){
        float s = x_lds[c2] * wx1 + bsum;
        if (c2 > 0) s += x_lds[c2-1] * wx0;
        if (c2 < 7) s += x_lds[c2+1] * wx2;
        g8[c2] += s;
      }
    }
    #pragma unroll
    for (int c2 = 0; c2 < 8; ++c2) P[gc][ih][c2] = g8[c2];
    __syncthreads();
    const float ipre = P[ic   ][0][col] + P[ic   ][1][col];
    const float fpre = P[ic+32][0][col] + P[ic+32][1][col];
    const float opre = P[ic+64][0][col] + P[ic+64][1][col];
    const float gpre = P[ic+96][0][col] + P[ic+96][1][col];
    const float cn = sigmoidf_(fpre)*c_reg + sigmoidf_(ipre)*tanhf(gpre);
    c_reg = cn;
    const float hn = sigmoidf_(opre)*tanhf(cn);
    hrawHi[((size_t)t*128 + b)*2048 + row*256 + tid] = (f16)hn;
    __syncthreads();
    h_lds[wofs] = hn;
  }
}

// ---------------------------------------------------------------------------
// Layer-1 ConvLSTM for ALL 64 steps. Packed-u32 LDS weights, padded h/x.
// Writes hrw1 hi only.
// ---------------------------------------------------------------------------
__global__ __launch_bounds__(256) void k_cell1_all(
    const f16* __restrict__ r0Hi, const f16* __restrict__ r0Lo,
    const float* __restrict__ h0s, const float* __restrict__ c0s,
    const unsigned int* __restrict__ wp32,     // [(icg*3+w)*128+gc]
    const float* __restrict__ cxb, const float* __restrict__ chb,
    f16* __restrict__ hrw1Hi)            // [T][B][2048]
{
  const int b = blockIdx.x >> 3, row = blockIdx.x & 7;
  const int tid = threadIdx.x;
  __shared__ float x_lds[264];
  __shared__ float h_lds[264];
  __shared__ float P[128][2][9];
  __shared__ unsigned int wlds32[96*128];      // 48 KB
  const int gc = tid >> 1, ih = tid & 1;
  for (int i = tid; i < 96*128; i += 256) wlds32[i] = wp32[i];
  const size_t dg = (size_t)b*2048 + row*256 + tid;
  const int ic = tid >> 3, col = tid & 7;
  const float bi = cxb[ic]    + chb[ic];
  const float bf = cxb[ic+32] + chb[ic+32];
  const float bo = cxb[ic+64] + chb[ic+64];
  const float bg = cxb[ic+96] + chb[ic+96];
  const int wofs = tid + ((tid >> 7) << 2);
  const int hbase = ih * 132;
  float c_reg = c0s[dg];
  h_lds[wofs] = h0s[dg];
  float xnext = (float)r0Hi[dg] + (float)r0Lo[dg];
  __syncthreads();
  for (int t = 0; t < 64; ++t){
    x_lds[wofs] = xnext;
    __syncthreads();
    if (t < 63)
      xnext = (float)r0Hi[(size_t)(t+1)*BD + dg] + (float)r0Lo[(size_t)(t+1)*BD + dg];
    {
      float g8[8];
      #pragma unroll
      for (int c2 = 0; c2 < 8; ++c2) g8[c2] = 0.f;
      #pragma unroll
      for (int icl = 0; icl < 16; ++icl){
        const int icg = ih*16 + icl;
        const float* hb = &h_lds[icl*8 + hbase];
        const float* xb = &x_lds[icl*8 + hbase];
        f32x4v hv0 = *reinterpret_cast<const f32x4v*>(hb);
        f32x4v hv1 = *reinterpret_cast<const f32x4v*>(hb + 4);
        f32x4v xv0 = *reinterpret_cast<const f32x4v*>(xb);
        f32x4v xv1 = *reinterpret_cast<const f32x4v*>(xb + 4);
        const float hv[8] = {hv0[0],hv0[1],hv0[2],hv0[3],hv1[0],hv1[1],hv1[2],hv1[3]};
        const float xv[8] = {xv0[0],xv0[1],xv0[2],xv0[3],xv1[0],xv1[1],xv1[2],xv1[3]};
        const unsigned int* wq = &wlds32[icg*3*128 + gc];
        const unsigned int w0 = wq[0], w1 = wq[128], w2 = wq[256];
        const float wh0 = bf2f((unsigned short)(w0 & 0xffffu));
        const float wh1 = bf2f((unsigned short)(w0 >> 16));
        const float wh2 = bf2f((unsigned short)(w1 & 0xffffu));
        const float wx0 = bf2f((unsigned short)(w1 >> 16));
        const float wx1 = bf2f((unsigned short)(w2 & 0xffffu));
        const float wx2 = bf2f((unsigned short)(w2 >> 16));
        #pragma unroll
        for (int c2 = 0; c2 < 8; ++c2){
          float s = hv[c2]*wh1 + xv[c2]*wx1;
          if (c2 > 0) s += hv[c2-1]*wh0 + xv[c2-1]*wx0;
          if (c2 < 7) s += hv[c2+1]*wh2 + xv[c2+1]*wx2;
          g8[c2] += s;
        }
      }
      #pragma unroll
      for (int c2 = 0; c2 < 8; ++c2) P[gc][ih][c2] = g8[c2];
    }
    __syncthreads();
    {
      const float ipre = P[ic   ][0][col] + P[ic   ][1][col] + bi;
      const float fpre = P[ic+32][0][col] + P[ic+32][1][col] + bf;
      const float opre = P[ic+64][0][col] + P[ic+64][1][col] + bo;
      const float gpre = P[ic+96][0][col] + P[ic+96][1][col] + bg;
      const float cn = sigmoidf_(fpre)*c_reg + sigmoidf_(ipre)*tanhf(gpre);
      c_reg = cn;
      const float hraw = sigmoidf_(opre)*tanhf(cn);
      hrw1Hi[(size_t)t*BD + dg] = (f16)hraw;
      __syncthreads();
      h_lds[wofs] = hraw;
    }
  }
}

// ---------------------------------------------------------------------------
// MFMA inter-attention: block (b, t-half of 32). Phase1 S=encF@st^T (K=2048,
// single-pass f16), phase2 column softmax, phase3 ctx = a^T @ enc via encT.
// Writes ctx hi only.
// ---------------------------------------------------------------------------
__global__ __launch_bounds__(256) void k_attn(
    const f16* __restrict__ encF,    // [128][128][2048]
    const f16* __restrict__ encT,    // [128][2048][128]
    const f16* __restrict__ stHi,    // [T][B][2048]
    f16* __restrict__ ctxHi)         // [T][B][2048]
{
  const int b = blockIdx.x, th = blockIdx.y;
  const int tid = threadIdx.x, lane = tid & 63, wv = tid >> 6;
  __shared__ float S_lds[128][36];
  __shared__ float red[8][32];
  __shared__ float colv[32];
  __shared__ __align__(16) char aT[8192];
  const int kb = lane >> 5;
  // ---- phase 1
  {
    const int rA = wv*32 + (lane & 31);
    const int tcol = th*32 + (lane & 31);
    const f16* pA  = encF + ((size_t)b*128 + rA)*2048 + kb*8;
    const f16* pBH = stHi + ((size_t)tcol*128 + b)*2048 + kb*8;
    f32x16 acc;
    #pragma unroll
    for (int r = 0; r < 16; ++r) acc[r] = 0.f;
    #pragma unroll 4
    for (int s = 0; s < 128; ++s){
      f16x8 av = *reinterpret_cast<const f16x8*>(pA  + s*16);
      f16x8 bh = *reinterpret_cast<const f16x8*>(pBH + s*16);
      acc = __builtin_amdgcn_mfma_f32_32x32x16_f16(av, bh, acc, 0, 0, 0);
    }
    #pragma unroll
    for (int r = 0; r < 16; ++r){
      const int rr = 4*kb + (r & 3) + 8*(r >> 2);
      S_lds[wv*32 + rr][lane & 31] = acc[r];
    }
  }
  __syncthreads();
  // ---- phase 2: column softmax
  {
    const int c = tid & 31, g = tid >> 5;
    float ev[16];
    float m = -INFINITY;
    #pragma unroll
    for (int i = 0; i < 16; ++i){ ev[i] = S_lds[g*16 + i][c]; m = fmaxf(m, ev[i]); }
    red[g][c] = m;
    __syncthreads();
    if (tid < 32){
      float M = red[0][tid];
      #pragma unroll
      for (int j = 1; j < 8; ++j) M = fmaxf(M, red[j][tid]);
      colv[tid] = M;
    }
    __syncthreads();
    const float M = colv[c];
    float sum = 0.f;
    #pragma unroll
    for (int i = 0; i < 16; ++i){ ev[i] = __expf(ev[i] - M); sum += ev[i]; }
    __syncthreads();
    red[g][c] = sum;
    __syncthreads();
    if (tid < 32){
      float L = red[0][tid];
      #pragma unroll
      for (int j = 1; j < 8; ++j) L += red[j][tid];
      colv[tid] = 1.f / L;
    }
    __syncthreads();
    const float inv = colv[c];
    f16x8 w0, w1;
    #pragma unroll
    for (int j = 0; j < 8; ++j){
      w0[j] = (f16)(ev[j] * inv);
      w1[j] = (f16)(ev[8 + j] * inv);
    }
    const int sw = (c & 15) << 4;
    *reinterpret_cast<f16x8*>(aT + c*256 + (((g*2    )*16) ^ sw)) = w0;
    *reinterpret_cast<f16x8*>(aT + c*256 + (((g*2 + 1)*16) ^ sw)) = w1;
  }
  __syncthreads();
  // ---- phase 3
  {
    const int arow = lane & 31;
    const int asw = (arow & 15) << 4;
    f16x8 afr[8];
    #pragma unroll
    for (int ks = 0; ks < 8; ++ks){
      const int chunk = 2*ks + kb;
      afr[ks] = *reinterpret_cast<const f16x8*>(aT + arow*256 + ((chunk*16) ^ asw));
    }
    for (int nt = wv; nt < 64; nt += 4){
      const int d = nt*32 + (lane & 31);
      const f16* pB = encT + ((size_t)b*2048 + d)*128 + kb*8;
      f32x16 acc;
      #pragma unroll
      for (int r = 0; r < 16; ++r) acc[r] = 0.f;
      #pragma unroll
      for (int ks = 0; ks < 8; ++ks){
        f16x8 bv = *reinterpret_cast<const f16x8*>(pB + ks*16);
        acc = __builtin_amdgcn_mfma_f32_32x32x16_f16(afr[ks], bv, acc, 0, 0, 0);
      }
      #pragma unroll
      for (int r = 0; r < 16; ++r){
        const int rr = 4*kb + (r & 3) + 8*(r >> 2);
        const size_t o = ((size_t)(th*32 + rr)*128 + b)*2048 + d;
        ctxHi[o] = (f16)acc[r];
      }
    }
  }
}

// ---------------------------------------------------------------------------
// Batched full-K ia GEMM (all t): p[t] = tanh([A0|A1]@W + bias), f16 hi/lo.
// Single-pass A. Grid (32 nt, 64 t). K=4096, global_load_lds double-buffer.
// ---------------------------------------------------------------------------
__global__ __launch_bounds__(256, 2) void k_gemm_full(
    const f16* __restrict__ a0, const f16* __restrict__ a1,
    const f16* __restrict__ wHp, const float* __restrict__ bias,
    f16* __restrict__ outHi, f16* __restrict__ outLo)
{
  const int nt = blockIdx.x, t = blockIdx.y;
  const size_t tb = (size_t)t * BD;
  const int tid = threadIdx.x;
  const int lane = tid & 63, wv = tid >> 6;
  // per buffer: A 16KB @0, W 8KB @16K; two buffers (48KB)
  __shared__ __align__(16) char lds[49152];
  const f16* wH = wHp + (size_t)(nt*64)*4096;

  auto stage = [&](int buf, int ki){
    char* lb = lds + buf*24576;
    const f16* aH = ((ki < 32) ? a0 : a1) + tb;
    const int ke = (ki & 31) * 64;
    #pragma unroll
    for (int i = 0; i < 4; ++i){
      const int c = i*256 + tid, row = c >> 3;
      const int srcb = ((c & 7)*16) ^ ((row & 7) << 4);
      g2l16((const char*)(aH + (size_t)row*2048 + ke) + srcb, lb + c*16);
    }
    #pragma unroll
    for (int i = 0; i < 2; ++i){
      const int c = i*256 + tid, row = c >> 3;
      const int srcb = ((c & 7)*16) ^ ((row & 7) << 4);
      g2l16((const char*)(wH + (size_t)row*4096 + ki*64) + srcb, lb + 16384 + c*16);
    }
  };

  f32x16 acc0, acc1;
  #pragma unroll
  for (int r = 0; r < 16; ++r){ acc0[r] = 0.f; acc1[r] = 0.f; }
  const int rA = wv*32 + (lane & 31);
  const int kb = lane >> 5;
  const int rB0 = lane & 31;
  const int aswz = (rA & 7) << 4;
  const int bswz = (rB0 & 7) << 4;

  stage(0, 0);
  __syncthreads();
  for (int ki = 0; ki < 64; ++ki){
    const int buf = ki & 1;
    if (ki < 63) stage(buf ^ 1, ki + 1);
    const char* lb = lds + buf*24576;
    #pragma unroll
    for (int s = 0; s < 4; ++s){
      const int cb = s*32 + kb*16;
      f16x8 ah  = *reinterpret_cast<const f16x8*>(lb + rA*128 + (cb ^ aswz));
      f16x8 b0h = *reinterpret_cast<const f16x8*>(lb + 16384 + rB0*128 + (cb ^ bswz));
      f16x8 b1h = *reinterpret_cast<const f16x8*>(lb + 16384 + 4096 + rB0*128 + (cb ^ bswz));
      acc0 = __builtin_amdgcn_mfma_f32_32x32x16_f16(ah, b0h, acc0, 0, 0, 0);
      acc1 = __builtin_amdgcn_mfma_f32_32x32x16_f16(ah, b1h, acc1, 0, 0, 0);
    }
    __syncthreads();
  }

  const int col0 = nt*64 + (lane & 31);
  const float b0 = bias[col0], b1 = bias[col0 + 32];
  const int rowBase = wv*32 + 4*kb;
  #pragma unroll
  for (int r = 0; r < 16; ++r){
    const int rr = rowBase + (r & 3) + 8*(r >> 2);
    const size_t o = tb + (size_t)rr*2048 + col0;
    const float p = tanhf(acc0[r] + b0);
    const float q = tanhf(acc1[r] + b1);
    const f16 ph = (f16)p, qh = (f16)q;
    outHi[o]      = ph;  outLo[o]      = (f16)(p - (float)ph);
    outHi[o + 32] = qh;  outLo[o + 32] = (f16)(q - (float)qh);
  }
}

// ---------------------------------------------------------------------------
// Batched sa GEMM (all t): A = p hi (single pass), W = [Wlow^T|Wup^T].
// nt<32 -> Y (f32, raw); nt>=32 -> G (f16). Grid (64 nt, 64 t), K=2048.
// ---------------------------------------------------------------------------
__global__ __launch_bounds__(256, 2) void k_gemm_full2(
    const f16* __restrict__ aHi,                                // [T][B][2048]
    const f16* __restrict__ wSp,                                // [4096][2048]
    float* __restrict__ Y, f16* __restrict__ G)                 // [T][B][2048]
{
  const int nt = blockIdx.x, t = blockIdx.y;
  const size_t tb = (size_t)t * BD;
  const int tid = threadIdx.x;
  const int lane = tid & 63, wv = tid >> 6;
  __shared__ __align__(16) char lds[49152];
  const f16* wH = wSp + (size_t)(nt*64)*2048;
  const f16* aH = aHi + tb;

  auto stage = [&](int buf, int ki){
    char* lb = lds + buf*24576;
    const int ke = ki*64;
    #pragma unroll
    for (int i = 0; i < 4; ++i){
      const int c = i*256 + tid, row = c >> 3;
      const int srcb = ((c & 7)*16) ^ ((row & 7) << 4);
      g2l16((const char*)(aH + (size_t)row*2048 + ke) + srcb, lb + c*16);
    }
    #pragma unroll
    for (int i = 0; i < 2; ++i){
      const int c = i*256 + tid, row = c >> 3;
      const int srcb = ((c & 7)*16) ^ ((row & 7) << 4);
      g2l16((const char*)(wH + (size_t)row*2048 + ke) + srcb, lb + 16384 + c*16);
    }
  };

  f32x16 acc0, acc1;
  #pragma unroll
  for (int r = 0; r < 16; ++r){ acc0[r] = 0.f; acc1[r] = 0.f; }
  const int rA = wv*32 + (lane & 31);
  const int kb = lane >> 5;
  const int rB0 = lane & 31;
  const int aswz = (rA & 7) << 4;
  const int bswz = (rB0 & 7) << 4;

  stage(0, 0);
  __syncthreads();
  for (int ki = 0; ki < 32; ++ki){
    const int buf = ki & 1;
    if (ki < 31) stage(buf ^ 1, ki + 1);
    const char* lb = lds + buf*24576;
    #pragma unroll
    for (int s = 0; s < 4; ++s){
      const int cb = s*32 + kb*16;
      f16x8 ah  = *reinterpret_cast<const f16x8*>(lb + rA*128 + (cb ^ aswz));
      f16x8 b0h = *reinterpret_cast<const f16x8*>(lb + 16384 + rB0*128 + (cb ^ bswz));
      f16x8 b1h = *reinterpret_cast<const f16x8*>(lb + 16384 + 4096 + rB0*128 + (cb ^ bswz));
      acc0 = __builtin_amdgcn_mfma_f32_32x32x16_f16(ah, b0h, acc0, 0, 0, 0);
      acc1 = __builtin_amdgcn_mfma_f32_32x32x16_f16(ah, b1h, acc1, 0, 0, 0);
    }
    __syncthreads();
  }

  const int col0 = nt*64 + (lane & 31);
  const int rowBase = wv*32 + 4*kb;
  if (nt < 32){
    float* yp = Y + tb + col0;
    #pragma unroll
    for (int r = 0; r < 16; ++r){
      const int rr = rowBase + (r & 3) + 8*(r >> 2);
      yp[(size_t)rr*2048]      = acc0[r];
      yp[(size_t)rr*2048 + 32] = acc1[r];
    }
  } else {
    f16* gp = G + tb + (col0 - 2048);
    #pragma unroll
    for (int r = 0; r < 16; ++r){
      const int rr = rowBase + (r & 3) + 8*(r >> 2);
      gp[(size_t)rr*2048]      = (f16)acc0[r];
      gp[(size_t)rr*2048 + 32] = (f16)acc1[r];
    }
  }
}

// ---------------------------------------------------------------------------
// Self-attention refine chain (persistent over t). Block per b, 512 threads.
// ---------------------------------------------------------------------------
__global__ __launch_bounds__(512) void k_selfchain(
    const f16* __restrict__ pHi, const f16* __restrict__ pLo,   // [T][B][2048]
    const float* __restrict__ Y, const f16* __restrict__ G,     // [T][B][2048]
    const float* __restrict__ bias,
    f16* __restrict__ rHi, f16* __restrict__ rLo)               // [T][B][2048]
{
  const int b = blockIdx.x;
  const int tid = threadIdx.x, lane = tid & 63, wv = tid >> 6;   // 8 waves
  __shared__ float sc[64];
  __shared__ float a_lds[64];
  const int d0 = tid * 4;
  f32x4v bb = *reinterpret_cast<const f32x4v*>(bias + d0);
  for (int t = 0; t < 64; ++t){
    const size_t pb = ((size_t)t*128 + b)*2048;
    if (t > 0){
      float hreg[32];
      #pragma unroll
      for (int jj = 0; jj < 4; ++jj){
        const int d = (jj*64 + lane)*8;
        f16x8 h8 = *reinterpret_cast<const f16x8*>(pHi + pb + d);
        f16x8 l8 = *reinterpret_cast<const f16x8*>(pLo + pb + d);
        #pragma unroll
        for (int j = 0; j < 8; ++j) hreg[jj*8+j] = (float)h8[j] + (float)l8[j];
      }
      for (int i = wv; i < t; i += 8){
        const f16* rh = rHi + ((size_t)i*128 + b)*2048;
        const f16* rl = rLo + ((size_t)i*128 + b)*2048;
        float dot = 0.f;
        #pragma unroll
        for (int jj = 0; jj < 4; ++jj){
          const int d = (jj*64 + lane)*8;
          f16x8 h8 = *reinterpret_cast<const f16x8*>(rh + d);
          f16x8 l8 = *reinterpret_cast<const f16x8*>(rl + d);
          #pragma unroll
          for (int j = 0; j < 8; ++j)
            dot += ((float)h8[j] + (float)l8[j]) * hreg[jj*8+j];
        }
        #pragma unroll
        for (int off = 1; off < 64; off <<= 1) dot += __shfl_xor(dot, off);
        if (lane == 0) sc[i] = dot;
      }
      __syncthreads();
      if (tid < 64){
        const float s = (tid < t) ? sc[tid] : -INFINITY;
        float mm = s;
        #pragma unroll
        for (int off = 1; off < 64; off <<= 1) mm = fmaxf(mm, __shfl_xor(mm, off));
        const float e = (tid < t) ? __expf(s - mm) : 0.f;
        float sum = e;
        #pragma unroll
        for (int off = 1; off < 64; off <<= 1) sum += __shfl_xor(sum, off);
        a_lds[tid] = e / sum;
      }
      __syncthreads();
    }
    float y[4];
    {
      f32x4v yv = *reinterpret_cast<const f32x4v*>(Y + (size_t)t*BD + (size_t)b*2048 + d0);
      #pragma unroll
      for (int j = 0; j < 4; ++j) y[j] = yv[j] + bb[j];
    }
    if (t > 0){
      for (int i = 0; i < t; ++i){
        const float a = a_lds[i];
        f16x4 g4 = *reinterpret_cast<const f16x4*>(G + ((size_t)i*128 + b)*2048 + d0);
        #pragma unroll
        for (int j = 0; j < 4; ++j) y[j] += a * (float)g4[j];
      }
    }
    f16x4 hh, ll;
    #pragma unroll
    for (int j = 0; j < 4; ++j){
      const float v = tanhf(y[j]);
      hh[j] = (f16)v;
      ll[j] = (f16)(v - (float)hh[j]);
    }
    *reinterpret_cast<f16x4*>(rHi + pb + d0) = hh;
    *reinterpret_cast<f16x4*>(rLo + pb + d0) = ll;
    __syncthreads();
  }
}

// ---------------------------------------------------------------------------
// Head stage 1: z1 = relu(r1(8192x2048) @ hw1 + hb1), single-pass f16 MFMA
// ---------------------------------------------------------------------------
__global__ __launch_bounds__(256) void k_headgemm(
    const f16* __restrict__ aHi,
    const f16* __restrict__ w1H,   // [224][2048]
    const float* __restrict__ hb1,
    float* __restrict__ z1)        // [8192][224]
{
  const int mb = blockIdx.x;
  const int nt = blockIdx.y;
  const int lane = threadIdx.x & 63, wv = threadIdx.x >> 6;
  const int rowA = mb*128 + wv*32 + (lane & 31);
  const int kb = lane >> 5;
  const int n = nt*32 + (lane & 31);
  const f16* pAH = aHi + (size_t)rowA*2048 + kb*8;
  const f16* pBH = w1H + (size_t)n*2048 + kb*8;
  f32x16 acc;
  #pragma unroll
  for (int r = 0; r < 16; ++r) acc[r] = 0.f;
  #pragma unroll 4
  for (int s = 0; s < 128; ++s){
    f16x8 ah = *reinterpret_cast<const f16x8*>(pAH + s*16);
    f16x8 bh = *reinterpret_cast<const f16x8*>(pBH + s*16);
    acc = __builtin_amdgcn_mfma_f32_32x32x16_f16(ah, bh, acc, 0, 0, 0);
  }
  const float bias = (n < 200) ? hb1[n] : 0.f;
  const int rowBase = mb*128 + wv*32 + 4*kb;
  #pragma unroll
  for (int r = 0; r < 16; ++r){
    const int rr = rowBase + (r & 3) + 8*(r >> 2);
    z1[(size_t)rr*224 + n] = fmaxf(acc[r] + bias, 0.f);
  }
}

// Head stage 2
__global__ __launch_bounds__(256) void k_head2(
    const float* __restrict__ z1,
    const float* __restrict__ hw2, const float* __restrict__ hb2,
    const float* __restrict__ hw3, const float* __restrict__ hb3,
    float* __restrict__ out)
{
  const int r0 = blockIdx.x * 64;
  const int tid = threadIdx.x;
  __shared__ float zl[64][200];
  __shared__ float z2[64][50];
  for (int i = tid; i < 64*200; i += 256){
    const int r = i / 200, n = i % 200;
    zl[r][n] = z1[(size_t)(r0 + r)*224 + n];
  }
  __syncthreads();
  for (int i = tid; i < 64*50; i += 256){
    const int r = i / 50, n = i % 50;
    float s = hb2[n];
    for (int k = 0; k < 200; ++k) s += zl[r][k] * hw2[k*50 + n];
    z2[r][n] = fmaxf(s, 0.f);
  }
  __syncthreads();
  for (int i = tid; i < 128; i += 256){
    const int r = i >> 1, c = i & 1;
    float s = hb3[c];
    for (int k = 0; k < 50; ++k) s += z2[r][k] * hw3[k*2 + c];
    const int rg = r0 + r;
    const int tt = rg >> 7, b = rg & 127;
    out[(size_t)b*128 + tt*2 + c] = s;
  }
}

// ---------------------------------------------------------------------------
extern "C" void kernel_launch(void* const* d_in, const int* in_sizes, int n_in,
                              void* d_out, int out_size, void* d_ws, size_t ws_size,
                              hipStream_t stream)
{
  (void)in_sizes; (void)n_in; (void)out_size; (void)ws_size;
  const float* x_flat = (const float*)d_in[0];
  const float* enc    = (const float*)d_in[1];
  const float* h0     = (const float*)d_in[2];
  const float* c0     = (const float*)d_in[3];
  const float* cx_w0  = (const float*)d_in[4];
  const float* cx_b0  = (const float*)d_in[5];
  const float* ch_w0  = (const float*)d_in[6];
  const float* ch_b0  = (const float*)d_in[7];
  const float* cx_w1  = (const float*)d_in[8];
  const float* cx_b1  = (const float*)d_in[9];
  const float* ch_w1  = (const float*)d_in[10];
  const float* ch_b1  = (const float*)d_in[11];
  const float* ia_w0  = (const float*)d_in[12];
  const float* ia_b0  = (const float*)d_in[13];
  const float* sa_w0  = (const float*)d_in[14];
  const float* sa_b0  = (const float*)d_in[15];
  const float* ia_w1  = (const float*)d_in[16];
  const float* ia_b1  = (const float*)d_in[17];
  const float* sa_w1  = (const float*)d_in[18];
  const float* sa_b1  = (const float*)d_in[19];
  const float* hw1    = (const float*)d_in[20];
  const float* hb1    = (const float*)d_in[21];
  const float* hw2    = (const float*)d_in[22];
  const float* hb2    = (const float*)d_in[23];
  const float* hw3    = (const float*)d_in[24];
  const float* hb3    = (const float*)d_in[25];
  float* out = (float*)d_out;

  char* ws = (char*)d_ws;
  size_t off = 0;
  auto alloc = [&](size_t bytes) -> char* {
    char* p = ws + off;
    off += (bytes + 255) & ~(size_t)255;
    return p;
  };
  const size_t WPLANE = (size_t)2048*4096*2;   // 16 MiB
  const size_t TPLANE = (size_t)64*BD*2;       // 32 MiB, [T][B][D] f16
  f16* wIa0 = (f16*)alloc(WPLANE);
  f16* wSa0 = (f16*)alloc(WPLANE);   // [4096][2048]: Wlow^T rows 0..2047, Wup^T rows 2048..
  f16* wIa1 = (f16*)alloc(WPLANE);
  f16* wSa1 = (f16*)alloc(WPLANE);
  f16* w1H  = (f16*)alloc((size_t)224*2048*2);
  f16* encF = (f16*)alloc((size_t)128*128*2048*2);   // 64 MiB
  f16* encT = (f16*)alloc((size_t)128*2048*128*2);   // 64 MiB
  f16* S1 = (f16*)alloc(TPLANE);
  f16* S2 = (f16*)alloc(TPLANE);
  f16* S3 = (f16*)alloc(TPLANE);
  f16* S4 = (f16*)alloc(TPLANE);
  f16* S5 = (f16*)alloc(TPLANE);
  f16* S6 = (f16*)alloc(TPLANE);
  f16* S7 = (f16*)alloc(TPLANE);
  f16* S8 = (f16*)alloc(TPLANE);
  unsigned int* wpack1 = (unsigned int*)alloc((size_t)96*128*4);
  // total ws ~= 449 MiB. Alias names (lifetimes verified disjoint):
  f16*  hr0AHi = S1;                         // hi only (lo plane dead)
  f16*  ctx0Hi = S3;
  f16*  p0Hi   = S5;  f16* p0Lo   = S6;
  float* Y0 = (float*)S1;                    // 64 MiB over S1+S2 (contiguous)
  f16*  G0  = S3;
  f16*  r0Hi = S7;    f16* r0Lo   = S8;
  f16*  hrw1Hi = S5;                         // hi only
  f16*  ctx1Hi = S1;
  f16*  p1Hi = S7;    f16* p1Lo   = S8;
  float* Y1 = (float*)S1;                    // 64 MiB over S1+S2
  f16*  G1  = S4;
  f16*  r1Hi = S5;    f16* r1Lo   = S3;
  float* z1 = (float*)wSa0;                  // head scratch (wSa0 dead by then)

  // ---- prologue -----------------------------------------------------------
  k_transpose_f16<<<dim3(64,128),256,0,stream>>>(ia_w0, wIa0, 4096, 2048);
  k_transpose_f16<<<dim3(64,128),256,0,stream>>>(ia_w1, wIa1, 4096, 2048);
  k_transpose_f16<<<dim3(64,64),256,0,stream>>>(sa_w0, wSa0, 2048, 2048);
  k_transpose_f16<<<dim3(64,64),256,0,stream>>>(sa_w0 + (size_t)2048*2048,
                                                wSa0 + (size_t)2048*2048, 2048, 2048);
  k_transpose_f16<<<dim3(64,64),256,0,stream>>>(sa_w1, wSa1, 2048, 2048);
  k_transpose_f16<<<dim3(64,64),256,0,stream>>>(sa_w1 + (size_t)2048*2048,
                                                wSa1 + (size_t)2048*2048, 2048, 2048);
  k_transpose_f16<<<dim3(7,64),256,0,stream>>>(hw1, w1H, 2048, 200);
  k_enc_prep<<<dim3(64,4,128),256,0,stream>>>(enc, encF, encT);
  k_pack_cellw<<<16,256,0,stream>>>(ch_w1, cx_w1, wpack1);

  // ---- layer 0 (fully batched + one persistent chain) ---------------------
  k_cell0<<<1024,256,0,stream>>>(x_flat, h0, c0, cx_w0, cx_b0, ch_w0, ch_b0,
                                 hr0AHi);
  k_attn<<<dim3(128,2),256,0,stream>>>(encF, encT, hr0AHi, ctx0Hi);
  k_gemm_full<<<dim3(32,64),256,0,stream>>>(hr0AHi, ctx0Hi,
                                            wIa0, ia_b0, p0Hi, p0Lo);
  k_gemm_full2<<<dim3(64,64),256,0,stream>>>(p0Hi, wSa0, Y0, G0);
  k_selfchain<<<128,512,0,stream>>>(p0Hi, p0Lo, Y0, G0, sa_b0, r0Hi, r0Lo);

  // ---- layer 1 (persistent cell + fully batched + one persistent chain) ---
  k_cell1_all<<<1024,256,0,stream>>>(r0Hi, r0Lo,
                                     h0 + (size_t)128*2048, c0 + (size_t)128*2048,
                                     wpack1, cx_b1, ch_b1, hrw1Hi);
  k_attn<<<dim3(128,2),256,0,stream>>>(encF, encT, hrw1Hi, ctx1Hi);
  k_gemm_full<<<dim3(32,64),256,0,stream>>>(hrw1Hi, ctx1Hi,
                                            wIa1, ia_b1, p1Hi, p1Lo);
  k_gemm_full2<<<dim3(64,64),256,0,stream>>>(p1Hi, wSa1, Y1, G1);
  k_selfchain<<<128,512,0,stream>>>(p1Hi, p1Lo, Y1, G1, sa_b1, r1Hi, r1Lo);

  // ---- head (batched over all t,b) ----------------------------------------
  k_headgemm<<<dim3(64,7),256,0,stream>>>(r1Hi, w1H, hb1, z1);
  k_head2<<<128,256,0,stream>>>(z1, hw2, hb2, hw3, hb3, out);
}